// Round 1
// baseline (3021.962 us; speedup 1.0000x reference)
//
#include <hip/hip_runtime.h>

#define BM 64
#define BN 64
#define BK 16
#define NTHR 256

struct GemmArgs {
  const float* A; const float* B; float* C;
  int lda, ldb, ldc;
  long sA, sB, sC;
  int M, N, K;
  int mode, tri;
  float* out2; long sOut2;
  const float* aux; int ldaux; long sAux;
  const float* rowv; long sRowv;
  const double* cd; long sCd;
  const float* kscale; long sKs;
  const float* clp; long sClp;
};

__device__ __forceinline__ float silu_f(float x){
  float s = 1.f/(1.f+expf(-x));
  return x*s;
}
__device__ __forceinline__ float silu_bwd_f(float x){
  float s = 1.f/(1.f+expf(-x));
  float si = x*s;
  return si + s*(1.f-si);
}

// LAYOUT: 0 = NN (A[m,k], B[k,n]), 1 = NT (A[m,k], B[n,k]), 2 = TN (A[k,m], B[k,n])
// modes: 0 +bias(aux[col])      1 C=acc, out2=silu(acc)        2 acc - aux[r,c]
//        3 silu_bwd(aux)*acc*rowv[r]   4 acc*rowv[r]
//        5 S-decay: (m>=l)? -acc*exp(cd[m]-cd[l]) : 0
//        6 same as 5 but *rowv[l]
//        7 C = silu(acc + C)    8 C += acc      9 C = acc + aux[r,c]*(*clp)
template<int LAYOUT>
__global__ __launch_bounds__(NTHR)
void gemm_kernel(GemmArgs g)
{
  const int bm = blockIdx.x, bn = blockIdx.y, bz = blockIdx.z;
  if (g.tri == 1 && bn < bm) return;   // strictly-below-diagonal S blocks: never written, never read
  const int row0 = bm*BM, col0 = bn*BN;
  int Keff = g.K;
  if (g.tri == 2) { Keff = row0 + BM; if (Keff > g.K) Keff = g.K; }

  const float* A   = g.A + (long)bz*g.sA;
  const float* Bp  = g.B + (long)bz*g.sB;
  float* C         = g.C + (long)bz*g.sC;
  const float* aux  = g.aux  ? g.aux  + (long)bz*g.sAux  : (const float*)0;
  const float* rowv = g.rowv ? g.rowv + (long)bz*g.sRowv : (const float*)0;
  float* out2       = g.out2 ? g.out2 + (long)bz*g.sOut2 : (float*)0;
  const double* cdp = g.cd   ? g.cd   + (long)bz*g.sCd   : (const double*)0;
  const float* ksp  = g.kscale ? g.kscale + (long)bz*g.sKs : (const float*)0;

  __shared__ float As[BK][BM+4];
  __shared__ float Bs[BK][BN+4];

  const int tid = threadIdx.x;
  float acc[4][4];
  #pragma unroll
  for (int i=0;i<4;i++)
    #pragma unroll
    for (int j=0;j<4;j++) acc[i][j]=0.f;

  for (int k0 = 0; k0 < Keff; k0 += BK) {
    // ---- stage A tile into As[k][m]
    if (LAYOUT == 2) {
      const int mm = tid & 63, kq = tid >> 6;
      #pragma unroll
      for (int p=0;p<4;p++){
        int kk = kq + 4*p;
        float v = A[(long)(k0+kk)*g.lda + row0 + mm];
        if (ksp) v *= ksp[k0+kk];
        As[kk][mm] = v;
      }
    } else {
      const int kk = tid & 15, mq = tid >> 4;
      #pragma unroll
      for (int p=0;p<4;p++){
        int mm = mq + 16*p;
        As[kk][mm] = A[(long)(row0+mm)*g.lda + k0 + kk];
      }
    }
    // ---- stage B tile into Bs[k][n]
    if (LAYOUT == 1) {
      const int kk = tid & 15, nq = tid >> 4;
      #pragma unroll
      for (int p=0;p<4;p++){
        int nn = nq + 16*p;
        Bs[kk][nn] = Bp[(long)(col0+nn)*g.ldb + k0 + kk];
      }
    } else {
      const int nn = tid & 63, kq = tid >> 6;
      #pragma unroll
      for (int p=0;p<4;p++){
        int kk = kq + 4*p;
        Bs[kk][nn] = Bp[(long)(k0+kk)*g.ldb + col0 + nn];
      }
    }
    __syncthreads();
    #pragma unroll
    for (int k=0;k<BK;k++){
      float4 av = *(const float4*)&As[k][4*(tid>>4)];
      float4 bv = *(const float4*)&Bs[k][4*(tid&15)];
      float a[4] = {av.x, av.y, av.z, av.w};
      float b[4] = {bv.x, bv.y, bv.z, bv.w};
      #pragma unroll
      for (int i=0;i<4;i++)
        #pragma unroll
        for (int j=0;j<4;j++)
          acc[i][j] = fmaf(a[i], b[j], acc[i][j]);
    }
    __syncthreads();
  }

  const int rb = row0 + 4*(tid>>4);
  const int cb = col0 + 4*(tid&15);
  const int mode = g.mode;

  if (mode == 5 || mode == 6) {
    #pragma unroll
    for (int i=0;i<4;i++){
      int r = rb + i;
      double cr = cdp[r];
      float lrv = rowv ? rowv[r] : 1.f;
      float vv[4];
      #pragma unroll
      for (int j=0;j<4;j++){
        int m = cb + j;
        float dec = (m >= r) ? expf((float)(cdp[m]-cr)) : 0.f;
        vv[j] = -acc[i][j]*dec*lrv;
      }
      float4 o = {vv[0],vv[1],vv[2],vv[3]};
      *(float4*)&C[(long)r*g.ldc + cb] = o;
    }
    return;
  }

  float clv = 0.f;
  if (mode == 9) clv = *(g.clp + (long)bz*g.sClp);

  #pragma unroll
  for (int i=0;i<4;i++){
    int r = rb + i;
    long co = (long)r*g.ldc + cb;
    float vv[4];
    #pragma unroll
    for (int j=0;j<4;j++) vv[j] = acc[i][j];

    if (mode == 0) {
      #pragma unroll
      for (int j=0;j<4;j++) vv[j] += aux[cb+j];
    } else if (mode == 1) {
      float4 o = {vv[0],vv[1],vv[2],vv[3]};
      *(float4*)&C[co] = o;
      #pragma unroll
      for (int j=0;j<4;j++) vv[j] = silu_f(vv[j]);
      float4 o2 = {vv[0],vv[1],vv[2],vv[3]};
      *(float4*)&out2[(long)r*g.ldc + cb] = o2;
      continue;
    } else if (mode == 2) {
      #pragma unroll
      for (int j=0;j<4;j++) vv[j] -= aux[(long)r*g.ldaux + cb + j];
    } else if (mode == 3) {
      float lrv = rowv[r];
      #pragma unroll
      for (int j=0;j<4;j++) vv[j] = silu_bwd_f(aux[(long)r*g.ldaux + cb + j]) * vv[j] * lrv;
    } else if (mode == 4) {
      float sc = rowv[r];
      #pragma unroll
      for (int j=0;j<4;j++) vv[j] *= sc;
    } else if (mode == 7) {
      float4 old = *(const float4*)&C[co];
      vv[0] = silu_f(vv[0]+old.x); vv[1] = silu_f(vv[1]+old.y);
      vv[2] = silu_f(vv[2]+old.z); vv[3] = silu_f(vv[3]+old.w);
    } else if (mode == 8) {
      float4 old = *(const float4*)&C[co];
      vv[0]+=old.x; vv[1]+=old.y; vv[2]+=old.z; vv[3]+=old.w;
    } else if (mode == 9) {
      #pragma unroll
      for (int j=0;j<4;j++) vv[j] += aux[(long)r*g.ldaux + cb + j]*clv;
    }
    float4 o = {vv[0],vv[1],vv[2],vv[3]};
    *(float4*)&C[co] = o;
  }
}

// Per-row dots x.w_lr, x.w_wd -> lr, log_wd. One wave per row.
__global__ __launch_bounds__(256)
void scalar_proj_kernel(const float* __restrict__ x,
                        const float* __restrict__ wlr, const float* __restrict__ blr,
                        const float* __restrict__ wwd, const float* __restrict__ bwd,
                        const float* __restrict__ lbl, const float* __restrict__ lbw,
                        float* __restrict__ lr, float* __restrict__ lw)
{
  const int row  = blockIdx.x*4 + (threadIdx.x >> 6);
  const int lane = threadIdx.x & 63;
  const float4 a = ((const float4*)(x + (long)row*256))[lane];
  const float4 u = ((const float4*)wlr)[lane];
  const float4 w = ((const float4*)wwd)[lane];
  float d1 = a.x*u.x + a.y*u.y + a.z*u.z + a.w*u.w;
  float d2 = a.x*w.x + a.y*w.y + a.z*w.z + a.w*w.w;
  #pragma unroll
  for (int off=32; off; off>>=1) {
    d1 += __shfl_down(d1, off);
    d2 += __shfl_down(d2, off);
  }
  if (lane == 0) {
    float s1 = 1.f/(1.f+expf(-(d1 + blr[0])));
    lr[row] = expf(lbl[0]) * s1;
    float s2 = 1.f/(1.f+expf(-(d2 + bwd[0])));
    lw[row] = logf(1.f - expf(lbw[0]) * s2);
  }
}

// Per-batch inclusive scan of log_wd (fp64), derived arrays.
__global__ __launch_bounds__(256)
void cumsum_kernel(const float* __restrict__ lw, const float* __restrict__ lr,
                   double* __restrict__ cd, float* __restrict__ wdc,
                   float* __restrict__ se1, float* __restrict__ se2, int L)
{
  const int b = blockIdx.x;
  const int t = threadIdx.x;
  const float* lwb = lw + (long)b*L;
  __shared__ double sum_s[256];
  double loc[8];
  double s = 0.0;
  #pragma unroll
  for (int i=0;i<8;i++){ s += (double)lwb[t*8+i]; loc[i] = s; }
  sum_s[t] = s;
  __syncthreads();
  for (int off=1; off<256; off<<=1){
    double v = 0.0;
    if (t >= off) v = sum_s[t-off];
    __syncthreads();
    sum_s[t] += v;
    __syncthreads();
  }
  const double prefix = (t > 0) ? sum_s[t-1] : 0.0;
  const double total  = sum_s[255];
  #pragma unroll
  for (int i=0;i<8;i++){
    double c = prefix + loc[i];
    long idx = (long)b*L + t*8 + i;
    cd[idx]  = c;
    wdc[idx] = (float)exp(c);
    double e = exp(total - c);
    se1[idx] = (float)(-e);
    se2[idx] = (float)(-e) * lr[idx];
  }
}

extern "C" void kernel_launch(void* const* d_in, const int* in_sizes, int n_in,
                              void* d_out, int out_size, void* d_ws, size_t ws_size,
                              hipStream_t stream)
{
  const int Bn = 4, L = 2048, D = 256, H = 512;
  const long LD = (long)L*D, LH = (long)L*H, HD = (long)H*D;

  const float* x   = (const float*)d_in[0];
  const float* W1  = (const float*)d_in[1];
  const float* W2  = (const float*)d_in[2];
  const float* Wq  = (const float*)d_in[3];
  const float* bq  = (const float*)d_in[4];
  const float* Wk  = (const float*)d_in[5];
  const float* bk  = (const float*)d_in[6];
  const float* Wv  = (const float*)d_in[7];
  const float* bv  = (const float*)d_in[8];
  const float* wlr = (const float*)d_in[9];
  const float* blr = (const float*)d_in[10];
  const float* wwd = (const float*)d_in[11];
  const float* bwd = (const float*)d_in[12];
  const float* lbl = (const float*)d_in[13];
  const float* lbw = (const float*)d_in[14];

  float* out0 = (float*)d_out;            // Z2_  [B,L,D]
  float* out1 = out0 + (long)Bn*LD;       // W1_next [B,H,D]
  float* out2 = out1 + (long)Bn*HD;       // W2_next [B,D,H]

  float* ws = (float*)d_ws;
  size_t off = 0;
  auto alloc = [&](size_t n){ float* p = ws + off; off += n; return p; };
  float* Qb  = alloc((size_t)Bn*LD);
  float* Kb  = alloc((size_t)Bn*LD);
  float* Vb  = alloc((size_t)Bn*LD);
  float* Z1  = alloc((size_t)Bn*LH);
  float* X2  = alloc((size_t)Bn*LH);
  float* gZ2 = alloc((size_t)Bn*LD);
  float* A1  = alloc((size_t)Bn*LH);
  float* Zt  = alloc((size_t)Bn*LH);
  float* lrb = alloc((size_t)Bn*L);
  float* lwb = alloc((size_t)Bn*L);
  float* wdc = alloc((size_t)Bn*L);
  float* se1 = alloc((size_t)Bn*L);
  float* se2 = alloc((size_t)Bn*L);
  double* cdb = (double*)alloc((size_t)2*Bn*L);
  float* S   = alloc((size_t)L*L);        // per-batch scratch, reused
  (void)ws_size; (void)in_sizes; (void)n_in; (void)out_size;

  auto launch = [&](int layout, const GemmArgs& g, int Z){
    dim3 grid(g.M/BM, g.N/BN, Z);
    if (layout == 0)      gemm_kernel<0><<<grid, NTHR, 0, stream>>>(g);
    else if (layout == 1) gemm_kernel<1><<<grid, NTHR, 0, stream>>>(g);
    else                  gemm_kernel<2><<<grid, NTHR, 0, stream>>>(g);
  };

  // 1. lr, log_wd
  scalar_proj_kernel<<<dim3(Bn*L/4), 256, 0, stream>>>(x, wlr, blr, wwd, bwd, lbl, lbw, lrb, lwb);
  // 2. cumsum (fp64) + wd_cross, -e, -lr*e
  cumsum_kernel<<<dim3(Bn), 256, 0, stream>>>(lwb, lrb, cdb, wdc, se1, se2, L);

  // 3. Q, K, V = x @ W + b   (NN, all batches as one M=8192)
  {
    const float* Wp[3] = {Wq, Wk, Wv};
    const float* bp[3] = {bq, bk, bv};
    float* Cp[3] = {Qb, Kb, Vb};
    for (int i=0;i<3;i++){
      GemmArgs g{};
      g.A = x; g.lda = D; g.B = Wp[i]; g.ldb = D; g.C = Cp[i]; g.ldc = D;
      g.M = Bn*L; g.N = D; g.K = D; g.mode = 0; g.aux = bp[i];
      launch(0, g, 1);
    }
  }
  // 4. Z1 = K . W1^T ; X2 = silu(Z1)  (NT, batched)
  {
    GemmArgs g{};
    g.A = Kb; g.lda = D; g.sA = LD; g.B = W1; g.ldb = D; g.sB = HD;
    g.C = Z1; g.ldc = H; g.sC = LH; g.M = L; g.N = H; g.K = D;
    g.mode = 1; g.out2 = X2; g.sOut2 = LH;
    launch(1, g, Bn);
  }
  // 5. gZ2 = X2 . W2^T - V  (NT, batched)
  {
    GemmArgs g{};
    g.A = X2; g.lda = H; g.sA = LH; g.B = W2; g.ldb = H; g.sB = HD;
    g.C = gZ2; g.ldc = D; g.sC = LD; g.M = L; g.N = D; g.K = H;
    g.mode = 2; g.aux = Vb; g.ldaux = D; g.sAux = LD;
    launch(1, g, Bn);
  }
  // 6. A1 = silu_bwd(Z1) * (gZ2 . W2) * lr   (NN, batched)
  {
    GemmArgs g{};
    g.A = gZ2; g.lda = D; g.sA = LD; g.B = W2; g.ldb = H; g.sB = HD;
    g.C = A1; g.ldc = H; g.sC = LH; g.M = L; g.N = H; g.K = D;
    g.mode = 3; g.aux = Z1; g.ldaux = H; g.sAux = LH; g.rowv = lrb; g.sRowv = L;
    launch(0, g, Bn);
  }
  // 7. Zt = wd_cross[m] * (Q . W1^T)   (Z1_cross, NT, batched)
  {
    GemmArgs g{};
    g.A = Qb; g.lda = D; g.sA = LD; g.B = W1; g.ldb = D; g.sB = HD;
    g.C = Zt; g.ldc = H; g.sC = LH; g.M = L; g.N = H; g.K = D;
    g.mode = 4; g.rowv = wdc; g.sRowv = L;
    launch(1, g, Bn);
  }
  // 8/9. per batch: S1 then Zt = silu(Zt + S1^T . A1)
  for (int b=0;b<Bn;b++){
    {
      GemmArgs g{};
      g.A = Kb + (long)b*LD; g.lda = D; g.B = Qb + (long)b*LD; g.ldb = D;
      g.C = S; g.ldc = L; g.M = L; g.N = L; g.K = D;
      g.mode = 5; g.tri = 1; g.cd = cdb + (long)b*L;
      launch(1, g, 1);
    }
    {
      GemmArgs g{};
      g.A = S; g.lda = L; g.B = A1 + (long)b*LH; g.ldb = H;
      g.C = Zt + (long)b*LH; g.ldc = H; g.M = L; g.N = H; g.K = L;
      g.mode = 7; g.tri = 2;
      launch(2, g, 1);
    }
  }
  // 10. out0 = wd_cross[m] * (X2_ . W2^T)   (Z2_cross, NT, batched; X2_ lives in Zt)
  {
    GemmArgs g{};
    g.A = Zt; g.lda = H; g.sA = LH; g.B = W2; g.ldb = H; g.sB = HD;
    g.C = out0; g.ldc = D; g.sC = LD; g.M = L; g.N = D; g.K = H;
    g.mode = 4; g.rowv = wdc; g.sRowv = L;
    launch(1, g, Bn);
  }
  // 11/12. per batch: S2 then out0 += S2^T . gZ2
  for (int b=0;b<Bn;b++){
    {
      GemmArgs g{};
      g.A = X2 + (long)b*LH; g.lda = H; g.B = Zt + (long)b*LH; g.ldb = H;
      g.C = S; g.ldc = L; g.M = L; g.N = L; g.K = H;
      g.mode = 6; g.tri = 1; g.cd = cdb + (long)b*L; g.rowv = lrb + (long)b*L;
      launch(1, g, 1);
    }
    {
      GemmArgs g{};
      g.A = S; g.lda = L; g.B = gZ2 + (long)b*LD; g.ldb = D;
      g.C = out0 + (long)b*LD; g.ldc = D; g.M = L; g.N = D; g.K = L;
      g.mode = 8; g.tri = 2;
      launch(2, g, 1);
    }
  }
  // 13. W1_next = (A1 * -e)^T . K + W1*cl   (TN, batched)
  {
    GemmArgs g{};
    g.A = A1; g.lda = H; g.sA = LH; g.kscale = se1; g.sKs = L;
    g.B = Kb; g.ldb = D; g.sB = LD;
    g.C = out1; g.ldc = D; g.sC = HD; g.M = H; g.N = D; g.K = L;
    g.mode = 9; g.aux = W1; g.ldaux = D; g.sAux = HD;
    g.clp = wdc + (L-1); g.sClp = L;
    launch(2, g, Bn);
  }
  // 14. W2_next = (gZ2 * -lr*e)^T . X2 + W2*cl   (TN, batched)
  {
    GemmArgs g{};
    g.A = gZ2; g.lda = D; g.sA = LD; g.kscale = se2; g.sKs = L;
    g.B = X2; g.ldb = H; g.sB = LH;
    g.C = out2; g.ldc = H; g.sC = HD; g.M = D; g.N = H; g.K = L;
    g.mode = 9; g.aux = W2; g.ldaux = H; g.sAux = HD;
    g.clp = wdc + (L-1); g.sClp = L;
    launch(2, g, Bn);
  }
}

// Round 2
// 1056.248 us; speedup vs baseline: 2.8610x; 2.8610x over previous
//
#include <hip/hip_runtime.h>

typedef __bf16 bf16;
typedef __bf16 bf16x8 __attribute__((ext_vector_type(8)));
typedef float  f32x4  __attribute__((ext_vector_type(4)));

#define BM 128
#define BN 128
#define BKT 32
#define SA 40   // LDS row stride (elems): 80B, 16B-aligned, 2-way-max banks

__device__ __forceinline__ float silu_f(float x){
  float s = 1.f/(1.f+__expf(-x));
  return x*s;
}
__device__ __forceinline__ float silu_bwd_f(float x){
  float s = 1.f/(1.f+__expf(-x));
  float si = x*s;
  return si + s*(1.f-si);
}

struct MArgs {
  const bf16* A; const bf16* B;
  long sA, sB;
  int lda, ldb;
  int M, N, K;
  int mode, tri;
  float* Cf; long sCf;
  bf16*  Cb; long sCb;
  bf16*  Cb2; long sCb2;
  int ldc;
  const float* auxf; int ldax; long sAuxf;
  const bf16*  auxb; long sAuxb;
  const float* rowv; long sRowv;
  const float* colv; long sColv;
  const double* cd;  long sCd;
  const float* ks;   long sKs;
  const float* clp;  long sClp;
};

// modes: 0 +bias(auxf[c]) -> Cb and/or Cf        1 Cb=acc, Cb2=silu(acc)
//        2 Cb=acc-auxf[r,c]                      3 Cb=silu_bwd(auxb[r,c])*acc*rowv[r]
//        4 Cf=acc*rowv[r]                        5 Cb=(c<=r)? -acc*exp(cd[r]-cd[c]) : 0
//        6 mode5 * colv[c]                       7 Cb=silu(acc + Cf[r,c])
//        9 Cf+=acc                              10 Cf=acc+auxf[r,c]*clv
__global__ __launch_bounds__(256)
void mfma_gemm(MArgs g)
{
  const int bm = blockIdx.x, bn = blockIdx.y, bz = blockIdx.z;
  if (g.tri == 1 && bn > bm) return;          // T is lower-triangular: upper blocks never read
  const int row0 = bm*BM, col0 = bn*BN;
  int Keff = g.K;
  if (g.tri == 2) { int ke = row0 + BM; if (ke < Keff) Keff = ke; }

  const bf16* A = g.A + (long)bz*g.sA;
  const bf16* B = g.B + (long)bz*g.sB;
  const float* ksp = g.ks ? g.ks + (long)bz*g.sKs : (const float*)0;
  const double* cd = g.cd ? g.cd + (long)bz*g.sCd : (const double*)0;
  float* Cf = g.Cf ? g.Cf + (long)bz*g.sCf : (float*)0;
  bf16* Cb  = g.Cb ? g.Cb + (long)bz*g.sCb : (bf16*)0;
  bf16* Cb2 = g.Cb2 ? g.Cb2 + (long)bz*g.sCb2 : (bf16*)0;
  const float* auxf = g.auxf ? g.auxf + (long)bz*g.sAuxf : (const float*)0;
  const bf16*  auxb = g.auxb ? g.auxb + (long)bz*g.sAuxb : (const bf16*)0;
  const float* rowv = g.rowv ? g.rowv + (long)bz*g.sRowv : (const float*)0;
  const float* colv = g.colv ? g.colv + (long)bz*g.sColv : (const float*)0;

  const int tid = threadIdx.x;
  const int mode = g.mode;

  // ---- decay-band producer skip: whole block underflows -> zero-fill, no K-loop
  if (mode == 5 || mode == 6) {
    float gm = (float)(cd[row0] - cd[col0 + BN - 1]);
    if (gm < -80.f) {
      bf16x8 z; 
      #pragma unroll
      for (int i=0;i<8;i++) z[i] = (bf16)0.f;
      const int rr = row0 + (tid>>1);
      const long base = (long)rr*g.ldc + col0 + (tid&1)*64;
      #pragma unroll
      for (int p=0;p<8;p++) *(bf16x8*)&Cb[base + p*8] = z;
      return;
    }
  }

  const int lane = tid & 63;
  const int w = tid >> 6;
  const int wr = (w >> 1) * 64, wc = (w & 1) * 64;
  const int l15 = lane & 15;
  const int quad = lane >> 4;

  __shared__ __align__(16) bf16 As[BM*SA];
  __shared__ __align__(16) bf16 Bs[BN*SA];

  f32x4 acc[4][4];
  #pragma unroll
  for (int i=0;i<4;i++)
    #pragma unroll
    for (int j=0;j<4;j++)
      #pragma unroll
      for (int r=0;r<4;r++) acc[i][j][r] = 0.f;

  const int mst = tid >> 1;
  const int kst = (tid & 1) * 16;

  // consumer K-tile skip (decay/se underflow)
  bool dosk = false; double cref = 0.0;
  if (cd && (mode == 7 || mode == 9)) { dosk = true; cref = cd[row0]; }
  if (cd && ksp)                       { dosk = true; cref = cd[g.K-1]; }

  for (int k0 = 0; k0 < Keff; k0 += BKT) {
    if (dosk && (cref - cd[k0 + BKT - 1] < -80.0)) continue;
    {
      const bf16* src = A + (long)(row0 + mst)*g.lda + k0 + kst;
      bf16x8 v0 = *(const bf16x8*)(src);
      bf16x8 v1 = *(const bf16x8*)(src + 8);
      if (ksp) {
        #pragma unroll
        for (int i=0;i<8;i++){
          v0[i] = (bf16)((float)v0[i] * ksp[k0+kst+i]);
          v1[i] = (bf16)((float)v1[i] * ksp[k0+kst+8+i]);
        }
      }
      *(bf16x8*)&As[mst*SA + kst]     = v0;
      *(bf16x8*)&As[mst*SA + kst + 8] = v1;
    }
    {
      const bf16* src = B + (long)(col0 + mst)*g.ldb + k0 + kst;
      bf16x8 v0 = *(const bf16x8*)(src);
      bf16x8 v1 = *(const bf16x8*)(src + 8);
      *(bf16x8*)&Bs[mst*SA + kst]     = v0;
      *(bf16x8*)&Bs[mst*SA + kst + 8] = v1;
    }
    __syncthreads();
    bf16x8 af[4], bfr[4];
    #pragma unroll
    for (int i=0;i<4;i++) af[i]  = *(const bf16x8*)&As[(wr + i*16 + l15)*SA + quad*8];
    #pragma unroll
    for (int j=0;j<4;j++) bfr[j] = *(const bf16x8*)&Bs[(wc + j*16 + l15)*SA + quad*8];
    #pragma unroll
    for (int i=0;i<4;i++)
      #pragma unroll
      for (int j=0;j<4;j++)
        acc[i][j] = __builtin_amdgcn_mfma_f32_16x16x32_bf16(af[i], bfr[j], acc[i][j], 0, 0, 0);
    __syncthreads();
  }

  float clv = 0.f;
  if (mode == 10) clv = *(g.clp + (long)bz*g.sClp);

  #pragma unroll
  for (int i=0;i<4;i++){
    const int rb = row0 + wr + i*16 + quad*4;
    #pragma unroll
    for (int j=0;j<4;j++){
      const int c = col0 + wc + j*16 + l15;
      #pragma unroll
      for (int reg=0; reg<4; reg++){
        const int r = rb + reg;
        float v = acc[i][j][reg];
        const long co = (long)r*g.ldc + c;
        switch (mode) {
          case 0: {
            float o = v + auxf[c];
            if (Cb) Cb[co] = (bf16)o;
            if (Cf) Cf[co] = o;
          } break;
          case 1: {
            Cb[co]  = (bf16)v;
            Cb2[co] = (bf16)silu_f(v);
          } break;
          case 2: {
            Cb[co] = (bf16)(v - auxf[(long)r*g.ldax + c]);
          } break;
          case 3: {
            Cb[co] = (bf16)(silu_bwd_f((float)auxb[(long)r*g.ldax + c]) * v * rowv[r]);
          } break;
          case 4: {
            Cf[co] = v * rowv[r];
          } break;
          case 5: {
            float o = (c <= r) ? -v*__expf((float)(cd[r]-cd[c])) : 0.f;
            Cb[co] = (bf16)o;
          } break;
          case 6: {
            float o = (c <= r) ? -v*colv[c]*__expf((float)(cd[r]-cd[c])) : 0.f;
            Cb[co] = (bf16)o;
          } break;
          case 7: {
            Cb[co] = (bf16)silu_f(v + Cf[co]);
          } break;
          case 9: {
            Cf[co] += v;
          } break;
          case 10: {
            Cf[co] = v + auxf[(long)r*g.ldax + c]*clv;
          } break;
        }
      }
    }
  }
}

// ---------- bf16 [R,C] -> [C,R] tiled transpose ----------
__global__ __launch_bounds__(256)
void transpose_bf16(const bf16* __restrict__ in, bf16* __restrict__ out,
                    int R, int C, long sIn, long sOut)
{
  __shared__ bf16 t[64][72];
  const bf16* ip = in + (long)blockIdx.z*sIn;
  bf16* op = out + (long)blockIdx.z*sOut;
  const int r0 = blockIdx.x*64, c0 = blockIdx.y*64;
  const int tid = threadIdx.x;
  const int lr_ = tid>>2, lc = (tid&3)*16;
  bf16x8 a = *(const bf16x8*)&ip[(long)(r0+lr_)*C + c0+lc];
  bf16x8 b = *(const bf16x8*)&ip[(long)(r0+lr_)*C + c0+lc+8];
  #pragma unroll
  for (int i=0;i<8;i++){ t[lr_][lc+i] = a[i]; t[lr_][lc+8+i] = b[i]; }
  __syncthreads();
  const int oc = tid>>2, orr = (tid&3)*16;
  bf16x8 u, v;
  #pragma unroll
  for (int i=0;i<8;i++){ u[i] = t[orr+i][oc]; v[i] = t[orr+8+i][oc]; }
  *(bf16x8*)&op[(long)(c0+oc)*R + r0+orr]     = u;
  *(bf16x8*)&op[(long)(c0+oc)*R + r0+orr+8]   = v;
}

// ---------- fp32 [R,C] -> bf16 [C,R] ----------
__global__ __launch_bounds__(256)
void transpose_f32_bf16(const float* __restrict__ in, bf16* __restrict__ out,
                        int R, int C, long sIn, long sOut)
{
  __shared__ bf16 t[64][72];
  const float* ip = in + (long)blockIdx.z*sIn;
  bf16* op = out + (long)blockIdx.z*sOut;
  const int r0 = blockIdx.x*64, c0 = blockIdx.y*64;
  const int tid = threadIdx.x;
  const int lr_ = tid>>2, lc = (tid&3)*16;
  #pragma unroll
  for (int q=0;q<4;q++){
    float4 a = *(const float4*)&ip[(long)(r0+lr_)*C + c0+lc + q*4];
    t[lr_][lc+q*4+0] = (bf16)a.x; t[lr_][lc+q*4+1] = (bf16)a.y;
    t[lr_][lc+q*4+2] = (bf16)a.z; t[lr_][lc+q*4+3] = (bf16)a.w;
  }
  __syncthreads();
  const int oc = tid>>2, orr = (tid&3)*16;
  bf16x8 u, v;
  #pragma unroll
  for (int i=0;i<8;i++){ u[i] = t[orr+i][oc]; v[i] = t[orr+8+i][oc]; }
  *(bf16x8*)&op[(long)(c0+oc)*R + r0+orr]   = u;
  *(bf16x8*)&op[(long)(c0+oc)*R + r0+orr+8] = v;
}

// ---------- fp32 -> bf16 elementwise ----------
__global__ __launch_bounds__(256)
void conv_f32_bf16(const float* __restrict__ in, bf16* __restrict__ out, long n)
{
  long i = ((long)blockIdx.x*256 + threadIdx.x)*8;
  if (i >= n) return;
  float4 a = *(const float4*)&in[i];
  float4 b = *(const float4*)&in[i+4];
  bf16x8 o;
  o[0]=(bf16)a.x; o[1]=(bf16)a.y; o[2]=(bf16)a.z; o[3]=(bf16)a.w;
  o[4]=(bf16)b.x; o[5]=(bf16)b.y; o[6]=(bf16)b.z; o[7]=(bf16)b.w;
  *(bf16x8*)&out[i] = o;
}

// ---------- per-row dots x.w_lr, x.w_wd -> lr, log_wd ----------
__global__ __launch_bounds__(256)
void scalar_proj_kernel(const float* __restrict__ x,
                        const float* __restrict__ wlr, const float* __restrict__ blr,
                        const float* __restrict__ wwd, const float* __restrict__ bwd,
                        const float* __restrict__ lbl, const float* __restrict__ lbw,
                        float* __restrict__ lr, float* __restrict__ lw)
{
  const int row  = blockIdx.x*4 + (threadIdx.x >> 6);
  const int lane = threadIdx.x & 63;
  const float4 a = ((const float4*)(x + (long)row*256))[lane];
  const float4 u = ((const float4*)wlr)[lane];
  const float4 w = ((const float4*)wwd)[lane];
  float d1 = a.x*u.x + a.y*u.y + a.z*u.z + a.w*u.w;
  float d2 = a.x*w.x + a.y*w.y + a.z*w.z + a.w*w.w;
  #pragma unroll
  for (int off=32; off; off>>=1) {
    d1 += __shfl_down(d1, off);
    d2 += __shfl_down(d2, off);
  }
  if (lane == 0) {
    float s1 = 1.f/(1.f+expf(-(d1 + blr[0])));
    lr[row] = expf(lbl[0]) * s1;
    float s2 = 1.f/(1.f+expf(-(d2 + bwd[0])));
    lw[row] = logf(1.f - expf(lbw[0]) * s2);
  }
}

// ---------- per-batch fp64 inclusive scan + derived arrays ----------
__global__ __launch_bounds__(256)
void cumsum_kernel(const float* __restrict__ lw, const float* __restrict__ lr,
                   double* __restrict__ cd, float* __restrict__ wdc,
                   float* __restrict__ se1, float* __restrict__ se2, int L)
{
  const int b = blockIdx.x;
  const int t = threadIdx.x;
  const float* lwb = lw + (long)b*L;
  __shared__ double sum_s[256];
  double loc[8];
  double s = 0.0;
  #pragma unroll
  for (int i=0;i<8;i++){ s += (double)lwb[t*8+i]; loc[i] = s; }
  sum_s[t] = s;
  __syncthreads();
  for (int off=1; off<256; off<<=1){
    double v = 0.0;
    if (t >= off) v = sum_s[t-off];
    __syncthreads();
    sum_s[t] += v;
    __syncthreads();
  }
  const double prefix = (t > 0) ? sum_s[t-1] : 0.0;
  const double total  = sum_s[255];
  #pragma unroll
  for (int i=0;i<8;i++){
    double c = prefix + loc[i];
    long idx = (long)b*L + t*8 + i;
    cd[idx]  = c;
    wdc[idx] = (float)exp(c);
    double e = exp(total - c);
    se1[idx] = (float)(-e);
    se2[idx] = (float)(-e) * lr[idx];
  }
}

extern "C" void kernel_launch(void* const* d_in, const int* in_sizes, int n_in,
                              void* d_out, int out_size, void* d_ws, size_t ws_size,
                              hipStream_t stream)
{
  const int Bn = 4, L = 2048, D = 256, H = 512;
  const long LD = (long)L*D, LH = (long)L*H, HD = (long)H*D, LL = (long)L*L;

  const float* x   = (const float*)d_in[0];
  const float* W1  = (const float*)d_in[1];
  const float* W2  = (const float*)d_in[2];
  const float* Wq  = (const float*)d_in[3];
  const float* bq  = (const float*)d_in[4];
  const float* Wk  = (const float*)d_in[5];
  const float* bk  = (const float*)d_in[6];
  const float* Wv  = (const float*)d_in[7];
  const float* bv  = (const float*)d_in[8];
  const float* wlr = (const float*)d_in[9];
  const float* blr = (const float*)d_in[10];
  const float* wwd = (const float*)d_in[11];
  const float* bwd = (const float*)d_in[12];
  const float* lbl = (const float*)d_in[13];
  const float* lbw = (const float*)d_in[14];
  (void)in_sizes; (void)n_in; (void)out_size; (void)ws_size;

  float* out0 = (float*)d_out;            // Z2_      [B,L,D]
  float* out1 = out0 + (long)Bn*LD;       // W1_next  [B,H,D]
  float* out2 = out1 + (long)Bn*HD;       // W2_next  [B,D,H]

  char* wsp = (char*)d_ws;
  size_t off = 0;
  auto alloc = [&](size_t bytes)->void*{
    void* p = wsp + off; off += (bytes + 255) & ~(size_t)255; return p;
  };
  bf16* xb   = (bf16*)alloc((size_t)Bn*LD*2);
  bf16* Wqt  = (bf16*)alloc((size_t)D*D*2);
  bf16* Wkt  = (bf16*)alloc((size_t)D*D*2);
  bf16* Wvt  = (bf16*)alloc((size_t)D*D*2);
  bf16* W1b  = (bf16*)alloc((size_t)Bn*HD*2);
  bf16* W2b  = (bf16*)alloc((size_t)Bn*HD*2);
  bf16* W2t  = (bf16*)alloc((size_t)Bn*HD*2);
  bf16* Qb   = (bf16*)alloc((size_t)Bn*LD*2);
  bf16* Kb   = (bf16*)alloc((size_t)Bn*LD*2);
  bf16* Kt   = (bf16*)alloc((size_t)Bn*LD*2);
  float* Vf  = (float*)alloc((size_t)Bn*LD*4);
  bf16* Z1b  = (bf16*)alloc((size_t)Bn*LH*2);
  bf16* X2b  = (bf16*)alloc((size_t)Bn*LH*2);
  bf16* X2t  = (bf16*)alloc((size_t)Bn*LH*2);
  bf16* gZb  = (bf16*)alloc((size_t)Bn*LD*2);
  bf16* gZt  = (bf16*)alloc((size_t)Bn*LD*2);
  bf16* A1b  = (bf16*)alloc((size_t)Bn*LH*2);
  bf16* A1t  = (bf16*)alloc((size_t)Bn*LH*2);
  bf16* X2_b = (bf16*)alloc((size_t)Bn*LH*2);
  float* Ztf = (float*)alloc((size_t)Bn*LH*4);
  bf16* Tb   = (bf16*)alloc((size_t)Bn*LL*2);
  float* lrb = (float*)alloc((size_t)Bn*L*4);
  float* lwb = (float*)alloc((size_t)Bn*L*4);
  float* wdc = (float*)alloc((size_t)Bn*L*4);
  float* se1 = (float*)alloc((size_t)Bn*L*4);
  float* se2 = (float*)alloc((size_t)Bn*L*4);
  double* cdb = (double*)alloc((size_t)Bn*L*8);

  auto run = [&](const MArgs& g, int Z){
    dim3 grid(g.M/BM, g.N/BN, Z);
    mfma_gemm<<<grid, 256, 0, stream>>>(g);
  };

  // ---- converts / small transposes
  conv_f32_bf16<<<dim3((Bn*LD)/8/256), 256, 0, stream>>>(x,  xb,  Bn*LD);
  conv_f32_bf16<<<dim3((Bn*HD)/8/256), 256, 0, stream>>>(W1, W1b, Bn*HD);
  conv_f32_bf16<<<dim3((Bn*HD)/8/256), 256, 0, stream>>>(W2, W2b, Bn*HD);
  transpose_f32_bf16<<<dim3(4,4,1), 256, 0, stream>>>(Wq, Wqt, D, D, 0, 0);
  transpose_f32_bf16<<<dim3(4,4,1), 256, 0, stream>>>(Wk, Wkt, D, D, 0, 0);
  transpose_f32_bf16<<<dim3(4,4,1), 256, 0, stream>>>(Wv, Wvt, D, D, 0, 0);
  transpose_f32_bf16<<<dim3(4,8,Bn), 256, 0, stream>>>(W2, W2t, D, H, HD, HD);

  // ---- scalars
  scalar_proj_kernel<<<dim3(Bn*L/4), 256, 0, stream>>>(x, wlr, blr, wwd, bwd, lbl, lbw, lrb, lwb);
  cumsum_kernel<<<dim3(Bn), 256, 0, stream>>>(lwb, lrb, cdb, wdc, se1, se2, L);

  // ---- QKV (M = B*L folded)
  {
    MArgs g{}; g.A = xb; g.lda = D; g.B = Wqt; g.ldb = D;
    g.M = Bn*L; g.N = D; g.K = D; g.mode = 0; g.ldc = D;
    g.auxf = bq; g.Cb = Qb; run(g, 1);
    g.B = Wkt; g.auxf = bk; g.Cb = Kb; run(g, 1);
    g.B = Wvt; g.auxf = bv; g.Cb = nullptr; g.Cf = Vf; run(g, 1);
  }
  transpose_bf16<<<dim3(32,4,Bn), 256, 0, stream>>>(Kb, Kt, L, D, LD, LD);

  // ---- Z1 = K.W1^T ; X2 = silu(Z1)
  {
    MArgs g{}; g.A = Kb; g.lda = D; g.sA = LD; g.B = W1b; g.ldb = D; g.sB = HD;
    g.M = L; g.N = H; g.K = D; g.mode = 1; g.ldc = H;
    g.Cb = Z1b; g.sCb = LH; g.Cb2 = X2b; g.sCb2 = LH; run(g, Bn);
  }
  transpose_bf16<<<dim3(32,8,Bn), 256, 0, stream>>>(X2b, X2t, L, H, LH, LH);

  // ---- gZ2 = X2.W2^T - V
  {
    MArgs g{}; g.A = X2b; g.lda = H; g.sA = LH; g.B = W2b; g.ldb = H; g.sB = HD;
    g.M = L; g.N = D; g.K = H; g.mode = 2; g.ldc = D;
    g.auxf = Vf; g.ldax = D; g.sAuxf = LD; g.Cb = gZb; g.sCb = LD; run(g, Bn);
  }
  transpose_bf16<<<dim3(32,4,Bn), 256, 0, stream>>>(gZb, gZt, L, D, LD, LD);

  // ---- A1 = silu_bwd(Z1)*(gZ2.W2)*lr
  {
    MArgs g{}; g.A = gZb; g.lda = D; g.sA = LD; g.B = W2t; g.ldb = D; g.sB = HD;
    g.M = L; g.N = H; g.K = D; g.mode = 3; g.ldc = H;
    g.auxb = Z1b; g.ldax = H; g.sAuxb = LH; g.rowv = lrb; g.sRowv = L;
    g.Cb = A1b; g.sCb = LH; run(g, Bn);
  }
  transpose_bf16<<<dim3(32,8,Bn), 256, 0, stream>>>(A1b, A1t, L, H, LH, LH);

  // ---- Ztf = wdc[m] * (Q.W1^T)   (Z1_cross)
  {
    MArgs g{}; g.A = Qb; g.lda = D; g.sA = LD; g.B = W1b; g.ldb = D; g.sB = HD;
    g.M = L; g.N = H; g.K = D; g.mode = 4; g.ldc = H;
    g.rowv = wdc; g.sRowv = L; g.Cf = Ztf; g.sCf = LH; run(g, Bn);
  }
  // ---- T1[m,l] = -(Q[m].K[l]) * exp(c[m]-c[l]) * (l<=m)
  {
    MArgs g{}; g.A = Qb; g.lda = D; g.sA = LD; g.B = Kb; g.ldb = D; g.sB = LD;
    g.M = L; g.N = L; g.K = D; g.mode = 5; g.tri = 1; g.ldc = L;
    g.cd = cdb; g.sCd = L; g.Cb = Tb; g.sCb = LL; run(g, Bn);
  }
  // ---- X2_ = silu(Ztf + T1 . A1)   (Z1_inner + cross)
  {
    MArgs g{}; g.A = Tb; g.lda = L; g.sA = LL; g.B = A1t; g.ldb = L; g.sB = LH;
    g.M = L; g.N = H; g.K = L; g.mode = 7; g.tri = 2; g.ldc = H;
    g.cd = cdb; g.sCd = L; g.Cf = Ztf; g.sCf = LH; g.Cb = X2_b; g.sCb = LH; run(g, Bn);
  }
  // ---- out0 = wdc[m] * (X2_ . W2^T)   (Z2_cross)
  {
    MArgs g{}; g.A = X2_b; g.lda = H; g.sA = LH; g.B = W2b; g.ldb = H; g.sB = HD;
    g.M = L; g.N = D; g.K = H; g.mode = 4; g.ldc = D;
    g.rowv = wdc; g.sRowv = L; g.Cf = out0; g.sCf = LD; run(g, Bn);
  }
  // ---- T2[m,l] = -lr[l]*(X2_[m].X2[l]) * exp(c[m]-c[l]) * (l<=m)
  {
    MArgs g{}; g.A = X2_b; g.lda = H; g.sA = LH; g.B = X2b; g.ldb = H; g.sB = LH;
    g.M = L; g.N = L; g.K = H; g.mode = 6; g.tri = 1; g.ldc = L;
    g.cd = cdb; g.sCd = L; g.colv = lrb; g.sColv = L; g.Cb = Tb; g.sCb = LL; run(g, Bn);
  }
  // ---- out0 += T2 . gZ2   (Z2_inner)
  {
    MArgs g{}; g.A = Tb; g.lda = L; g.sA = LL; g.B = gZt; g.ldb = L; g.sB = LD;
    g.M = L; g.N = D; g.K = L; g.mode = 9; g.tri = 2; g.ldc = D;
    g.cd = cdb; g.sCd = L; g.Cf = out0; g.sCf = LD; run(g, Bn);
  }
  // ---- W1_next = (A1t * se1) . Kt^T + W1*wdc[L-1]
  {
    MArgs g{}; g.A = A1t; g.lda = L; g.sA = LH; g.B = Kt; g.ldb = L; g.sB = LD;
    g.M = H; g.N = D; g.K = L; g.mode = 10; g.ldc = D;
    g.ks = se1; g.sKs = L; g.cd = cdb; g.sCd = L;
    g.auxf = W1; g.ldax = D; g.sAuxf = HD; g.clp = wdc + (L-1); g.sClp = L;
    g.Cf = out1; g.sCf = HD; run(g, Bn);
  }
  // ---- W2_next = (gZt * se2) . X2t^T + W2*wdc[L-1]
  {
    MArgs g{}; g.A = gZt; g.lda = L; g.sA = LD; g.B = X2t; g.ldb = L; g.sB = LH;
    g.M = D; g.N = H; g.K = L; g.mode = 10; g.ldc = H;
    g.ks = se2; g.sKs = L; g.cd = cdb; g.sCd = L;
    g.auxf = W2; g.ldax = H; g.sAuxf = HD; g.clp = wdc + (L-1); g.sClp = L;
    g.Cf = out2; g.sCf = HD; run(g, Bn);
  }
}

// Round 3
// 429.349 us; speedup vs baseline: 7.0385x; 2.4601x over previous
//
#include <hip/hip_runtime.h>

typedef __bf16 bf16;
typedef __bf16 bf16x8 __attribute__((ext_vector_type(8)));
typedef float  f32x4  __attribute__((ext_vector_type(4)));

#define SA 40    // LDS row stride for 32-wide k tiles
#define SP 136   // LDS row stride for P (128 wide)

__device__ __forceinline__ float silu_f(float x){
  float s = 1.f/(1.f+__expf(-x));
  return x*s;
}
__device__ __forceinline__ float silu_bwd_f(float x){
  float s = 1.f/(1.f+__expf(-x));
  float si = x*s;
  return si + s*(1.f-si);
}

// ===================== generic 128x128 MFMA GEMM (NT) =====================
struct MArgs {
  const bf16* A; const bf16* B;
  long sA, sB;
  int lda, ldb;
  int M, N, K;
  int mode;
  float* Cf; long sCf;
  bf16*  Cb; long sCb;
  bf16*  Cb2; long sCb2;
  int ldc;
  const float* auxf; int ldax; long sAuxf;
  const bf16*  auxb; long sAuxb;
  const float* rowv; long sRowv;
  const double* cd;  long sCd;
  const float* ks;   long sKs;
  const float* clp;  long sClp;
  // mode 11 (QKV): route by column
  bf16* Q; bf16* Ko; float* Vo; const float* bqkv;
};

// modes: 1 Cb=acc, Cb2=silu(acc)        2 Cb=acc-auxf[r,c]
//        3 Cb=silu_bwd(auxb[r,c])*acc*rowv[r]
//        10 Cf=acc+auxf[r,c]*clv (A scaled by ks[k], k-tiles skipped when dead)
//        11 QKV: c<256->Q, <512->Ko, else->Vo(+bias all)
__global__ __launch_bounds__(256)
void mfma_gemm(MArgs g)
{
  const int bm = blockIdx.x, bn = blockIdx.y, bz = blockIdx.z;
  const int row0 = bm*128, col0 = bn*128;

  const bf16* A = g.A + (long)bz*g.sA;
  const bf16* B = g.B + (long)bz*g.sB;
  const float* ksp = g.ks ? g.ks + (long)bz*g.sKs : (const float*)0;
  const double* cd = g.cd ? g.cd + (long)bz*g.sCd : (const double*)0;
  float* Cf = g.Cf ? g.Cf + (long)bz*g.sCf : (float*)0;
  bf16* Cb  = g.Cb ? g.Cb + (long)bz*g.sCb : (bf16*)0;
  bf16* Cb2 = g.Cb2 ? g.Cb2 + (long)bz*g.sCb2 : (bf16*)0;
  const float* auxf = g.auxf ? g.auxf + (long)bz*g.sAuxf : (const float*)0;
  const bf16*  auxb = g.auxb ? g.auxb + (long)bz*g.sAuxb : (const bf16*)0;
  const float* rowv = g.rowv ? g.rowv + (long)bz*g.sRowv : (const float*)0;

  const int tid = threadIdx.x;
  const int mode = g.mode;
  const int lane = tid & 63;
  const int w = tid >> 6;
  const int wr = (w >> 1) * 64, wc = (w & 1) * 64;
  const int l15 = lane & 15;
  const int quad = lane >> 4;

  __shared__ __align__(16) bf16 As[128*SA];
  __shared__ __align__(16) bf16 Bs[128*SA];

  f32x4 acc[4][4];
  #pragma unroll
  for (int i=0;i<4;i++)
    #pragma unroll
    for (int j=0;j<4;j++)
      #pragma unroll
      for (int r=0;r<4;r++) acc[i][j][r] = 0.f;

  const int mst = tid >> 1;
  const int kst = (tid & 1) * 16;
  const bool dosk = (cd && ksp);
  const double cref = dosk ? cd[g.K-1] : 0.0;

  for (int k0 = 0; k0 < g.K; k0 += 32) {
    if (dosk && (cref - cd[k0 + 31] < -45.0)) continue;
    {
      const bf16* src = A + (long)(row0 + mst)*g.lda + k0 + kst;
      bf16x8 v0 = *(const bf16x8*)(src);
      bf16x8 v1 = *(const bf16x8*)(src + 8);
      if (ksp) {
        #pragma unroll
        for (int i=0;i<8;i++){
          v0[i] = (bf16)((float)v0[i] * ksp[k0+kst+i]);
          v1[i] = (bf16)((float)v1[i] * ksp[k0+kst+8+i]);
        }
      }
      *(bf16x8*)&As[mst*SA + kst]     = v0;
      *(bf16x8*)&As[mst*SA + kst + 8] = v1;
    }
    {
      const bf16* src = B + (long)(col0 + mst)*g.ldb + k0 + kst;
      bf16x8 v0 = *(const bf16x8*)(src);
      bf16x8 v1 = *(const bf16x8*)(src + 8);
      *(bf16x8*)&Bs[mst*SA + kst]     = v0;
      *(bf16x8*)&Bs[mst*SA + kst + 8] = v1;
    }
    __syncthreads();
    bf16x8 af[4], bfr[4];
    #pragma unroll
    for (int i=0;i<4;i++) af[i]  = *(const bf16x8*)&As[(wr + i*16 + l15)*SA + quad*8];
    #pragma unroll
    for (int j=0;j<4;j++) bfr[j] = *(const bf16x8*)&Bs[(wc + j*16 + l15)*SA + quad*8];
    #pragma unroll
    for (int i=0;i<4;i++)
      #pragma unroll
      for (int j=0;j<4;j++)
        acc[i][j] = __builtin_amdgcn_mfma_f32_16x16x32_bf16(af[i], bfr[j], acc[i][j], 0, 0, 0);
    __syncthreads();
  }

  float clv = 0.f;
  if (mode == 10) clv = *(g.clp + (long)bz*g.sClp);

  #pragma unroll
  for (int i=0;i<4;i++){
    const int rb = row0 + wr + i*16 + quad*4;
    #pragma unroll
    for (int j=0;j<4;j++){
      const int c = col0 + wc + j*16 + l15;
      #pragma unroll
      for (int reg=0; reg<4; reg++){
        const int r = rb + reg;
        float v = acc[i][j][reg];
        const long co = (long)r*g.ldc + c;
        switch (mode) {
          case 1: {
            Cb[co]  = (bf16)v;
            Cb2[co] = (bf16)silu_f(v);
          } break;
          case 2: {
            Cb[co] = (bf16)(v - auxf[(long)r*g.ldax + c]);
          } break;
          case 3: {
            Cb[co] = (bf16)(silu_bwd_f((float)auxb[(long)r*g.ldax + c]) * v * rowv[r]);
          } break;
          case 10: {
            Cf[co] = v + auxf[(long)r*g.ldax + c]*clv;
          } break;
          case 11: {
            float o = v + g.bqkv[c];
            if (c < 256)      g.Q [(long)r*256 + c]       = (bf16)o;
            else if (c < 512) g.Ko[(long)r*256 + (c-256)] = (bf16)o;
            else              g.Vo[(long)r*256 + (c-512)] = o;
          } break;
        }
      }
    }
  }
}

// ===================== fused inner kernel =====================
// O = wdc[m] * (A . W^T)                                  (cross term)
//   + sum_{l-tiles in band} P . B2[:, l]                  (inner term)
// where P[m,l] = -(A[m] . B1[l]) * exp(cd[m]-cd[l]) * (l<=m) * (ISF2? lr[l]:1)
// F1 (ISF2=0): A=Q, B1=K, B2=A1t, W=W1b, out Cb = silu(O)    [X2_]
// F2 (ISF2=1): A=X2_, B1=X2, B2=gZt, W=W2b, out Cf = O       [Z2_]
struct FArgs {
  const bf16 *A, *B1, *B2, *W;
  long sA, sB1, sB2, sW;
  int ldb2;
  const double* cd; long sCd;
  const float* colv; long sColv;
  const float* wdc; long sWdc;
  float* Cf; long sCf;
  bf16* Cb; long sCb;
  int ldc;
};

template<int KSTEPS, int ISF2>
__global__ __launch_bounds__(256)
void fused_inner(FArgs g)
{
  const int m0 = blockIdx.x*128, n0 = blockIdx.y*128, bz = blockIdx.z;
  const int K1 = KSTEPS*32;
  const bf16* A  = g.A  + (long)bz*g.sA;
  const bf16* B1 = g.B1 + (long)bz*g.sB1;
  const bf16* B2 = g.B2 + (long)bz*g.sB2;
  const bf16* W  = g.W  + (long)bz*g.sW;
  const double* cd = g.cd + (long)bz*g.sCd;
  const float* colv = ISF2 ? (g.colv + (long)bz*g.sColv) : (const float*)0;
  const float* wdc = g.wdc + (long)bz*g.sWdc;

  const int tid = threadIdx.x;
  const int lane = tid & 63, w = tid >> 6;
  const int wr = (w>>1)*64, wc = (w&1)*64;
  const int l15 = lane & 15, quad = lane >> 4;
  const int mst = tid >> 1, kst = (tid & 1)*16;

  __shared__ __align__(16) bf16 Asx[128*SA];
  __shared__ __align__(16) bf16 Bsx[128*SA];
  __shared__ __align__(16) bf16 Ps[128*SP];

  f32x4 O[4][4];
  #pragma unroll
  for (int i=0;i<4;i++)
    #pragma unroll
    for (int j=0;j<4;j++)
      #pragma unroll
      for (int r=0;r<4;r++) O[i][j][r] = 0.f;

  // ---- init phase: O = A . W^T
  for (int ks=0; ks<KSTEPS; ks++){
    const int k0 = ks*32;
    {
      const bf16* src = A + (long)(m0+mst)*K1 + k0 + kst;
      *(bf16x8*)&Asx[mst*SA + kst]   = *(const bf16x8*)(src);
      *(bf16x8*)&Asx[mst*SA + kst+8] = *(const bf16x8*)(src+8);
    }
    {
      const bf16* src = W + (long)(n0+mst)*K1 + k0 + kst;
      *(bf16x8*)&Bsx[mst*SA + kst]   = *(const bf16x8*)(src);
      *(bf16x8*)&Bsx[mst*SA + kst+8] = *(const bf16x8*)(src+8);
    }
    __syncthreads();
    bf16x8 af[4], bfr[4];
    #pragma unroll
    for (int i=0;i<4;i++) af[i]  = *(const bf16x8*)&Asx[(wr + i*16 + l15)*SA + quad*8];
    #pragma unroll
    for (int j=0;j<4;j++) bfr[j] = *(const bf16x8*)&Bsx[(wc + j*16 + l15)*SA + quad*8];
    #pragma unroll
    for (int i=0;i<4;i++)
      #pragma unroll
      for (int j=0;j<4;j++)
        O[i][j] = __builtin_amdgcn_mfma_f32_16x16x32_bf16(af[i], bfr[j], O[i][j], 0, 0, 0);
    __syncthreads();
  }
  // scale cross term by wdc[m]
  #pragma unroll
  for (int i=0;i<4;i++)
    #pragma unroll
    for (int reg=0; reg<4; reg++){
      const float s = wdc[m0 + wr + i*16 + quad*4 + reg];
      #pragma unroll
      for (int j=0;j<4;j++) O[i][j][reg] *= s;
    }

  // ---- banded l-loop
  int lb = 0;
  {
    const double cm = cd[m0];
    while (lb < m0 && (cm - cd[lb+127]) < -45.0) lb += 128;
  }
  for (int l0 = lb; l0 <= m0; l0 += 128) {
    f32x4 P[4][4];
    #pragma unroll
    for (int i=0;i<4;i++)
      #pragma unroll
      for (int j=0;j<4;j++)
        #pragma unroll
        for (int r=0;r<4;r++) P[i][j][r] = 0.f;

    for (int ks=0; ks<KSTEPS; ks++){
      const int k0 = ks*32;
      {
        const bf16* src = A + (long)(m0+mst)*K1 + k0 + kst;
        *(bf16x8*)&Asx[mst*SA + kst]   = *(const bf16x8*)(src);
        *(bf16x8*)&Asx[mst*SA + kst+8] = *(const bf16x8*)(src+8);
      }
      {
        const bf16* src = B1 + (long)(l0+mst)*K1 + k0 + kst;
        *(bf16x8*)&Bsx[mst*SA + kst]   = *(const bf16x8*)(src);
        *(bf16x8*)&Bsx[mst*SA + kst+8] = *(const bf16x8*)(src+8);
      }
      __syncthreads();
      bf16x8 af[4], bfr[4];
      #pragma unroll
      for (int i=0;i<4;i++) af[i]  = *(const bf16x8*)&Asx[(wr + i*16 + l15)*SA + quad*8];
      #pragma unroll
      for (int j=0;j<4;j++) bfr[j] = *(const bf16x8*)&Bsx[(wc + j*16 + l15)*SA + quad*8];
      #pragma unroll
      for (int i=0;i<4;i++)
        #pragma unroll
        for (int j=0;j<4;j++)
          P[i][j] = __builtin_amdgcn_mfma_f32_16x16x32_bf16(af[i], bfr[j], P[i][j], 0, 0, 0);
      __syncthreads();
    }
    // decay mask -> Ps (bf16)
    {
      float cl[4];
      #pragma unroll
      for (int j=0;j<4;j++) cl[j] = (float)cd[l0 + wc + j*16 + l15];
      float lrv[4];
      if (ISF2) {
        #pragma unroll
        for (int j=0;j<4;j++) lrv[j] = colv[l0 + wc + j*16 + l15];
      }
      #pragma unroll
      for (int i=0;i<4;i++)
        #pragma unroll
        for (int reg=0; reg<4; reg++){
          const int mloc = wr + i*16 + quad*4 + reg;
          const int m = m0 + mloc;
          const float cm2 = (float)cd[m];
          #pragma unroll
          for (int j=0;j<4;j++){
            const int lloc = wc + j*16 + l15;
            const int l = l0 + lloc;
            float v = -P[i][j][reg] * __expf(cm2 - cl[j]);
            if (ISF2) v *= lrv[j];
            if (l > m) v = 0.f;
            Ps[mloc*SP + lloc] = (bf16)v;
          }
        }
    }
    __syncthreads();
    // O += P . B2-tile
    for (int ks2=0; ks2<4; ks2++){
      {
        const bf16* src = B2 + (long)(n0+mst)*g.ldb2 + l0 + ks2*32 + kst;
        *(bf16x8*)&Bsx[mst*SA + kst]   = *(const bf16x8*)(src);
        *(bf16x8*)&Bsx[mst*SA + kst+8] = *(const bf16x8*)(src+8);
      }
      __syncthreads();
      bf16x8 af[4], bfr[4];
      #pragma unroll
      for (int i=0;i<4;i++) af[i]  = *(const bf16x8*)&Ps[(wr + i*16 + l15)*SP + ks2*32 + quad*8];
      #pragma unroll
      for (int j=0;j<4;j++) bfr[j] = *(const bf16x8*)&Bsx[(wc + j*16 + l15)*SA + quad*8];
      #pragma unroll
      for (int i=0;i<4;i++)
        #pragma unroll
        for (int j=0;j<4;j++)
          O[i][j] = __builtin_amdgcn_mfma_f32_16x16x32_bf16(af[i], bfr[j], O[i][j], 0, 0, 0);
      __syncthreads();
    }
  }

  // ---- epilogue
  #pragma unroll
  for (int i=0;i<4;i++){
    const int rb = m0 + wr + i*16 + quad*4;
    #pragma unroll
    for (int j=0;j<4;j++){
      const int c = n0 + wc + j*16 + l15;
      #pragma unroll
      for (int reg=0; reg<4; reg++){
        const long co = (long)(rb+reg)*g.ldc + c;
        if (ISF2) g.Cf[(long)bz*g.sCf + co] = O[i][j][reg];
        else      g.Cb[(long)bz*g.sCb + co] = (bf16)silu_f(O[i][j][reg]);
      }
    }
  }
}

// ===================== helpers =====================
__global__ __launch_bounds__(256)
void transpose_bf16(const bf16* __restrict__ in, bf16* __restrict__ out,
                    int R, int C, long sIn, long sOut)
{
  __shared__ bf16 t[64][72];
  const bf16* ip = in + (long)blockIdx.z*sIn;
  bf16* op = out + (long)blockIdx.z*sOut;
  const int r0 = blockIdx.x*64, c0 = blockIdx.y*64;
  const int tid = threadIdx.x;
  const int lr_ = tid>>2, lc = (tid&3)*16;
  bf16x8 a = *(const bf16x8*)&ip[(long)(r0+lr_)*C + c0+lc];
  bf16x8 b = *(const bf16x8*)&ip[(long)(r0+lr_)*C + c0+lc+8];
  #pragma unroll
  for (int i=0;i<8;i++){ t[lr_][lc+i] = a[i]; t[lr_][lc+8+i] = b[i]; }
  __syncthreads();
  const int oc = tid>>2, orr = (tid&3)*16;
  bf16x8 u, v;
  #pragma unroll
  for (int i=0;i<8;i++){ u[i] = t[orr+i][oc]; v[i] = t[orr+8+i][oc]; }
  *(bf16x8*)&op[(long)(c0+oc)*R + r0+orr]     = u;
  *(bf16x8*)&op[(long)(c0+oc)*R + r0+orr+8]   = v;
}

__global__ __launch_bounds__(256)
void transpose_f32_bf16(const float* __restrict__ in, bf16* __restrict__ out,
                        int R, int C, long sIn, long sOut)
{
  __shared__ bf16 t[64][72];
  const float* ip = in + (long)blockIdx.z*sIn;
  bf16* op = out + (long)blockIdx.z*sOut;
  const int r0 = blockIdx.x*64, c0 = blockIdx.y*64;
  const int tid = threadIdx.x;
  const int lr_ = tid>>2, lc = (tid&3)*16;
  #pragma unroll
  for (int q=0;q<4;q++){
    float4 a = *(const float4*)&ip[(long)(r0+lr_)*C + c0+lc + q*4];
    t[lr_][lc+q*4+0] = (bf16)a.x; t[lr_][lc+q*4+1] = (bf16)a.y;
    t[lr_][lc+q*4+2] = (bf16)a.z; t[lr_][lc+q*4+3] = (bf16)a.w;
  }
  __syncthreads();
  const int oc = tid>>2, orr = (tid&3)*16;
  bf16x8 u, v;
  #pragma unroll
  for (int i=0;i<8;i++){ u[i] = t[orr+i][oc]; v[i] = t[orr+8+i][oc]; }
  *(bf16x8*)&op[(long)(c0+oc)*R + r0+orr]   = u;
  *(bf16x8*)&op[(long)(c0+oc)*R + r0+orr+8] = v;
}

__global__ __launch_bounds__(256)
void conv_f32_bf16(const float* __restrict__ in, bf16* __restrict__ out, long n)
{
  long i = ((long)blockIdx.x*256 + threadIdx.x)*8;
  if (i >= n) return;
  float4 a = *(const float4*)&in[i];
  float4 b = *(const float4*)&in[i+4];
  bf16x8 o;
  o[0]=(bf16)a.x; o[1]=(bf16)a.y; o[2]=(bf16)a.z; o[3]=(bf16)a.w;
  o[4]=(bf16)b.x; o[5]=(bf16)b.y; o[6]=(bf16)b.z; o[7]=(bf16)b.w;
  *(bf16x8*)&out[i] = o;
}

__global__ void concat_bias(const float* __restrict__ bq, const float* __restrict__ bk,
                            const float* __restrict__ bv, float* __restrict__ o)
{
  int t = threadIdx.x;
  o[t] = (t<256) ? bq[t] : ((t<512) ? bk[t-256] : bv[t-512]);
}

__global__ __launch_bounds__(256)
void scalar_proj_kernel(const float* __restrict__ x,
                        const float* __restrict__ wlr, const float* __restrict__ blr,
                        const float* __restrict__ wwd, const float* __restrict__ bwd,
                        const float* __restrict__ lbl, const float* __restrict__ lbw,
                        float* __restrict__ lr, float* __restrict__ lw)
{
  const int row  = blockIdx.x*4 + (threadIdx.x >> 6);
  const int lane = threadIdx.x & 63;
  const float4 a = ((const float4*)(x + (long)row*256))[lane];
  const float4 u = ((const float4*)wlr)[lane];
  const float4 w = ((const float4*)wwd)[lane];
  float d1 = a.x*u.x + a.y*u.y + a.z*u.z + a.w*u.w;
  float d2 = a.x*w.x + a.y*w.y + a.z*w.z + a.w*w.w;
  #pragma unroll
  for (int off=32; off; off>>=1) {
    d1 += __shfl_down(d1, off);
    d2 += __shfl_down(d2, off);
  }
  if (lane == 0) {
    float s1 = 1.f/(1.f+expf(-(d1 + blr[0])));
    lr[row] = expf(lbl[0]) * s1;
    float s2 = 1.f/(1.f+expf(-(d2 + bwd[0])));
    lw[row] = logf(1.f - expf(lbw[0]) * s2);
  }
}

__global__ __launch_bounds__(256)
void cumsum_kernel(const float* __restrict__ lw, const float* __restrict__ lr,
                   double* __restrict__ cd, float* __restrict__ wdc,
                   float* __restrict__ se1, float* __restrict__ se2, int L)
{
  const int b = blockIdx.x;
  const int t = threadIdx.x;
  const float* lwb = lw + (long)b*L;
  __shared__ double sum_s[256];
  double loc[8];
  double s = 0.0;
  #pragma unroll
  for (int i=0;i<8;i++){ s += (double)lwb[t*8+i]; loc[i] = s; }
  sum_s[t] = s;
  __syncthreads();
  for (int off=1; off<256; off<<=1){
    double v = 0.0;
    if (t >= off) v = sum_s[t-off];
    __syncthreads();
    sum_s[t] += v;
    __syncthreads();
  }
  const double prefix = (t > 0) ? sum_s[t-1] : 0.0;
  const double total  = sum_s[255];
  #pragma unroll
  for (int i=0;i<8;i++){
    double c = prefix + loc[i];
    long idx = (long)b*L + t*8 + i;
    cd[idx]  = c;
    wdc[idx] = (float)exp(c);
    double e = exp(total - c);
    se1[idx] = (float)(-e);
    se2[idx] = (float)(-e) * lr[idx];
  }
}

extern "C" void kernel_launch(void* const* d_in, const int* in_sizes, int n_in,
                              void* d_out, int out_size, void* d_ws, size_t ws_size,
                              hipStream_t stream)
{
  const int Bn = 4, L = 2048, D = 256, H = 512;
  const long LD = (long)L*D, LH = (long)L*H, HD = (long)H*D;

  const float* x   = (const float*)d_in[0];
  const float* W1  = (const float*)d_in[1];
  const float* W2  = (const float*)d_in[2];
  const float* Wq  = (const float*)d_in[3];
  const float* bq  = (const float*)d_in[4];
  const float* Wk  = (const float*)d_in[5];
  const float* bk  = (const float*)d_in[6];
  const float* Wv  = (const float*)d_in[7];
  const float* bv  = (const float*)d_in[8];
  const float* wlr = (const float*)d_in[9];
  const float* blr = (const float*)d_in[10];
  const float* wwd = (const float*)d_in[11];
  const float* bwd = (const float*)d_in[12];
  const float* lbl = (const float*)d_in[13];
  const float* lbw = (const float*)d_in[14];
  (void)in_sizes; (void)n_in; (void)out_size; (void)ws_size;

  float* out0 = (float*)d_out;            // Z2_      [B,L,D]
  float* out1 = out0 + (long)Bn*LD;       // W1_next  [B,H,D]
  float* out2 = out1 + (long)Bn*HD;       // W2_next  [B,D,H]

  char* wsp = (char*)d_ws;
  size_t off = 0;
  auto alloc = [&](size_t bytes)->void*{
    void* p = wsp + off; off += (bytes + 255) & ~(size_t)255; return p;
  };
  bf16* xb    = (bf16*)alloc((size_t)Bn*LD*2);
  bf16* Wqkvt = (bf16*)alloc((size_t)3*D*D*2);
  float* bqkv = (float*)alloc((size_t)3*D*4);
  bf16* W1b  = (bf16*)alloc((size_t)Bn*HD*2);
  bf16* W2b  = (bf16*)alloc((size_t)Bn*HD*2);
  bf16* W2t  = (bf16*)alloc((size_t)Bn*HD*2);
  bf16* Qb   = (bf16*)alloc((size_t)Bn*LD*2);
  bf16* Kb   = (bf16*)alloc((size_t)Bn*LD*2);
  bf16* Kt   = (bf16*)alloc((size_t)Bn*LD*2);
  float* Vf  = (float*)alloc((size_t)Bn*LD*4);
  bf16* Z1b  = (bf16*)alloc((size_t)Bn*LH*2);
  bf16* X2b  = (bf16*)alloc((size_t)Bn*LH*2);
  bf16* X2t  = (bf16*)alloc((size_t)Bn*LH*2);
  bf16* gZb  = (bf16*)alloc((size_t)Bn*LD*2);
  bf16* gZt  = (bf16*)alloc((size_t)Bn*LD*2);
  bf16* A1b  = (bf16*)alloc((size_t)Bn*LH*2);
  bf16* A1t  = (bf16*)alloc((size_t)Bn*LH*2);
  bf16* X2_b = (bf16*)alloc((size_t)Bn*LH*2);
  float* lrb = (float*)alloc((size_t)Bn*L*4);
  float* lwb = (float*)alloc((size_t)Bn*L*4);
  float* wdc = (float*)alloc((size_t)Bn*L*4);
  float* se1 = (float*)alloc((size_t)Bn*L*4);
  float* se2 = (float*)alloc((size_t)Bn*L*4);
  double* cdb = (double*)alloc((size_t)Bn*L*8);

  auto run = [&](const MArgs& g, int Z){
    dim3 grid(g.M/128, g.N/128, Z);
    mfma_gemm<<<grid, 256, 0, stream>>>(g);
  };

  // ---- converts / weight transposes
  conv_f32_bf16<<<dim3((Bn*LD)/8/256), 256, 0, stream>>>(x,  xb,  Bn*LD);
  conv_f32_bf16<<<dim3((Bn*HD)/8/256), 256, 0, stream>>>(W1, W1b, Bn*HD);
  conv_f32_bf16<<<dim3((Bn*HD)/8/256), 256, 0, stream>>>(W2, W2b, Bn*HD);
  transpose_f32_bf16<<<dim3(4,4,1), 256, 0, stream>>>(Wq, Wqkvt,         D, D, 0, 0);
  transpose_f32_bf16<<<dim3(4,4,1), 256, 0, stream>>>(Wk, Wqkvt + D*D,   D, D, 0, 0);
  transpose_f32_bf16<<<dim3(4,4,1), 256, 0, stream>>>(Wv, Wqkvt + 2*D*D, D, D, 0, 0);
  transpose_f32_bf16<<<dim3(4,8,Bn), 256, 0, stream>>>(W2, W2t, D, H, HD, HD);
  concat_bias<<<dim3(1), 768, 0, stream>>>(bq, bk, bv, bqkv);

  // ---- scalars
  scalar_proj_kernel<<<dim3(Bn*L/4), 256, 0, stream>>>(x, wlr, blr, wwd, bwd, lbl, lbw, lrb, lwb);
  cumsum_kernel<<<dim3(Bn), 256, 0, stream>>>(lwb, lrb, cdb, wdc, se1, se2, L);

  // ---- fused QKV (M = B*L, N = 768)
  {
    MArgs g{}; g.A = xb; g.lda = D; g.B = Wqkvt; g.ldb = D;
    g.M = Bn*L; g.N = 3*D; g.K = D; g.mode = 11; g.ldc = 0;
    g.Q = Qb; g.Ko = Kb; g.Vo = Vf; g.bqkv = bqkv;
    run(g, 1);
  }
  transpose_bf16<<<dim3(32,4,Bn), 256, 0, stream>>>(Kb, Kt, L, D, LD, LD);

  // ---- Z1 = K.W1^T ; X2 = silu(Z1)
  {
    MArgs g{}; g.A = Kb; g.lda = D; g.sA = LD; g.B = W1b; g.ldb = D; g.sB = HD;
    g.M = L; g.N = H; g.K = D; g.mode = 1; g.ldc = H;
    g.Cb = Z1b; g.sCb = LH; g.Cb2 = X2b; g.sCb2 = LH; run(g, Bn);
  }
  transpose_bf16<<<dim3(32,8,Bn), 256, 0, stream>>>(X2b, X2t, L, H, LH, LH);

  // ---- gZ2 = X2.W2^T - V
  {
    MArgs g{}; g.A = X2b; g.lda = H; g.sA = LH; g.B = W2b; g.ldb = H; g.sB = HD;
    g.M = L; g.N = D; g.K = H; g.mode = 2; g.ldc = D;
    g.auxf = Vf; g.ldax = D; g.sAuxf = LD; g.Cb = gZb; g.sCb = LD; run(g, Bn);
  }
  transpose_bf16<<<dim3(32,4,Bn), 256, 0, stream>>>(gZb, gZt, L, D, LD, LD);

  // ---- A1 = silu_bwd(Z1)*(gZ2.W2)*lr
  {
    MArgs g{}; g.A = gZb; g.lda = D; g.sA = LD; g.B = W2t; g.ldb = D; g.sB = HD;
    g.M = L; g.N = H; g.K = D; g.mode = 3; g.ldc = H;
    g.auxb = Z1b; g.ldax = H; g.sAuxb = LH; g.rowv = lrb; g.sRowv = L;
    g.Cb = A1b; g.sCb = LH; run(g, Bn);
  }
  transpose_bf16<<<dim3(32,8,Bn), 256, 0, stream>>>(A1b, A1t, L, H, LH, LH);

  // ---- F1: X2_ = silu( wdc[m]*(Q.W1^T) + sum_l P1.A1 )
  {
    FArgs f{};
    f.A = Qb;  f.sA = LD;  f.B1 = Kb;  f.sB1 = LD;
    f.B2 = A1t; f.sB2 = LH; f.ldb2 = L;
    f.W = W1b; f.sW = HD;
    f.cd = cdb; f.sCd = L; f.wdc = wdc; f.sWdc = L;
    f.Cb = X2_b; f.sCb = LH; f.ldc = H;
    fused_inner<8,0><<<dim3(L/128, H/128, Bn), 256, 0, stream>>>(f);
  }
  // ---- F2: out0 = wdc[m]*(X2_.W2^T) + sum_l P2.gZ2
  {
    FArgs f{};
    f.A = X2_b; f.sA = LH; f.B1 = X2b; f.sB1 = LH;
    f.B2 = gZt; f.sB2 = LD; f.ldb2 = L;
    f.W = W2b; f.sW = HD;
    f.cd = cdb; f.sCd = L; f.colv = lrb; f.sColv = L; f.wdc = wdc; f.sWdc = L;
    f.Cf = out0; f.sCf = LD; f.ldc = D;
    fused_inner<16,1><<<dim3(L/128, D/128, Bn), 256, 0, stream>>>(f);
  }
  // ---- W1_next = (A1t * se1) . Kt^T + W1*wdc[L-1]
  {
    MArgs g{}; g.A = A1t; g.lda = L; g.sA = LH; g.B = Kt; g.ldb = L; g.sB = LD;
    g.M = H; g.N = D; g.K = L; g.mode = 10; g.ldc = D;
    g.ks = se1; g.sKs = L; g.cd = cdb; g.sCd = L;
    g.auxf = W1; g.ldax = D; g.sAuxf = HD; g.clp = wdc + (L-1); g.sClp = L;
    g.Cf = out1; g.sCf = HD; run(g, Bn);
  }
  // ---- W2_next = (gZt * se2) . X2t^T + W2*wdc[L-1]
  {
    MArgs g{}; g.A = gZt; g.lda = L; g.sA = LD; g.B = X2t; g.ldb = L; g.sB = LH;
    g.M = D; g.N = H; g.K = L; g.mode = 10; g.ldc = H;
    g.ks = se2; g.sKs = L; g.cd = cdb; g.sCd = L;
    g.auxf = W2; g.ldax = H; g.sAuxf = HD; g.clp = wdc + (L-1); g.sClp = L;
    g.Cf = out2; g.sCf = HD; run(g, Bn);
  }
}

// Round 6
// 336.355 us; speedup vs baseline: 8.9845x; 1.2765x over previous
//
#include <hip/hip_runtime.h>

typedef __bf16 bf16;
typedef __bf16 bf16x8 __attribute__((ext_vector_type(8)));
typedef float  f32x4  __attribute__((ext_vector_type(4)));

#define SA 40    // LDS row stride (elems) for 32-wide k tiles
#define SP 136   // LDS row stride (elems) for Ps (128 wide)

__device__ __forceinline__ float silu_f(float x){
  float s = 1.f/(1.f+__expf(-x));
  return x*s;
}
__device__ __forceinline__ float silu_bwd_f(float x){
  float s = 1.f/(1.f+__expf(-x));
  float si = x*s;
  return si + s*(1.f-si);
}

// ===================== generic 128x64 MFMA GEMM (NT), R3-style loop =====================
struct MArgs {
  const bf16* A; const bf16* B;
  long sA, sB;
  int lda, ldb;
  int M, N, K;
  int mode;
  float* Cf; long sCf;
  bf16*  Cb; long sCb;
  bf16*  Cb2; long sCb2;
  int ldc;
  const float* auxf; int ldax; long sAuxf;
  const bf16*  auxb; long sAuxb;
  const float* rowv; long sRowv;
  const double* cd;  long sCd;
  const float* ks;   long sKs;
  const float* clp;  long sClp;
  bf16* Q; bf16* Ko; float* Vo; const float* bqkv;   // mode 11
};

// modes: 1 Cb=acc, Cb2=silu(acc)   2 Cb=acc-auxf[r,c]
//        3 Cb=silu_bwd(auxb[r,c])*acc*rowv[r]
//        10 Cf=acc+auxf[r,c]*clv (A scaled by ks[k], dead k-prefix skipped)
//        11 QKV: c<256->Q, <512->Ko, else->Vo (+bias)
__global__ __launch_bounds__(256)
void mfma_gemm(MArgs g)
{
  const int bm = blockIdx.x, bn = blockIdx.y, bz = blockIdx.z;
  const int row0 = bm*128, col0 = bn*64;

  const bf16* A = g.A + (long)bz*g.sA;
  const bf16* B = g.B + (long)bz*g.sB;
  const float* ksp = g.ks ? g.ks + (long)bz*g.sKs : (const float*)0;
  const double* cd = g.cd ? g.cd + (long)bz*g.sCd : (const double*)0;
  float* Cf = g.Cf ? g.Cf + (long)bz*g.sCf : (float*)0;
  bf16* Cb  = g.Cb ? g.Cb + (long)bz*g.sCb : (bf16*)0;
  bf16* Cb2 = g.Cb2 ? g.Cb2 + (long)bz*g.sCb2 : (bf16*)0;
  const float* auxf = g.auxf ? g.auxf + (long)bz*g.sAuxf : (const float*)0;
  const bf16*  auxb = g.auxb ? g.auxb + (long)bz*g.sAuxb : (const bf16*)0;
  const float* rowv = g.rowv ? g.rowv + (long)bz*g.sRowv : (const float*)0;

  const int tid = threadIdx.x;
  const int mode = g.mode;
  const int lane = tid & 63;
  const int w = tid >> 6;
  const int wr = (w >> 1) * 64, wc = (w & 1) * 32;
  const int l15 = lane & 15;
  const int quad = lane >> 4;

  __shared__ __align__(16) bf16 As[128*SA];
  __shared__ __align__(16) bf16 Bs[64*SA];

  f32x4 acc[4][2];
  #pragma unroll
  for (int i=0;i<4;i++)
    #pragma unroll
    for (int j=0;j<2;j++)
      #pragma unroll
      for (int r=0;r<4;r++) acc[i][j][r] = 0.f;

  const int rowA = tid >> 1, kA = (tid & 1) * 16;   // 128x32 tile, 16 elems/thr
  const int rowB = tid >> 2, kB = (tid & 3) * 8;    // 64x32 tile, 8 elems/thr

  int klo = 0;
  if (cd && ksp) {
    const double cref = cd[g.K-1];
    while (klo + 32 < g.K && (cref - cd[klo+31]) < -45.0) klo += 32;
  }

  for (int k0 = klo; k0 < g.K; k0 += 32) {
    {
      const bf16* src = A + (long)(row0+rowA)*g.lda + k0 + kA;
      bf16x8 v0 = *(const bf16x8*)(src);
      bf16x8 v1 = *(const bf16x8*)(src + 8);
      if (ksp) {
        #pragma unroll
        for (int i=0;i<8;i++){
          v0[i] = (bf16)((float)v0[i] * ksp[k0+kA+i]);
          v1[i] = (bf16)((float)v1[i] * ksp[k0+kA+8+i]);
        }
      }
      *(bf16x8*)&As[rowA*SA + kA]     = v0;
      *(bf16x8*)&As[rowA*SA + kA + 8] = v1;
    }
    {
      bf16x8 b0 = *(const bf16x8*)(B + (long)(col0+rowB)*g.ldb + k0 + kB);
      *(bf16x8*)&Bs[rowB*SA + kB] = b0;
    }
    __syncthreads();
    bf16x8 af[4], bf2[2];
    #pragma unroll
    for (int i=0;i<4;i++) af[i]  = *(const bf16x8*)&As[(wr + i*16 + l15)*SA + quad*8];
    #pragma unroll
    for (int j=0;j<2;j++) bf2[j] = *(const bf16x8*)&Bs[(wc + j*16 + l15)*SA + quad*8];
    #pragma unroll
    for (int i=0;i<4;i++)
      #pragma unroll
      for (int j=0;j<2;j++)
        acc[i][j] = __builtin_amdgcn_mfma_f32_16x16x32_bf16(af[i], bf2[j], acc[i][j], 0, 0, 0);
    __syncthreads();
  }

  float clv = 0.f;
  if (mode == 10) clv = *(g.clp + (long)bz*g.sClp);

  #pragma unroll
  for (int i=0;i<4;i++){
    const int rb = row0 + wr + i*16 + quad*4;
    #pragma unroll
    for (int j=0;j<2;j++){
      const int c = col0 + wc + j*16 + l15;
      #pragma unroll
      for (int reg=0; reg<4; reg++){
        const int r = rb + reg;
        float v = acc[i][j][reg];
        const long co = (long)r*g.ldc + c;
        switch (mode) {
          case 1: {
            Cb[co]  = (bf16)v;
            Cb2[co] = (bf16)silu_f(v);
          } break;
          case 2: {
            Cb[co] = (bf16)(v - auxf[(long)r*g.ldax + c]);
          } break;
          case 3: {
            Cb[co] = (bf16)(silu_bwd_f((float)auxb[(long)r*g.ldax + c]) * v * rowv[r]);
          } break;
          case 10: {
            Cf[co] = v + auxf[(long)r*g.ldax + c]*clv;
          } break;
          case 11: {
            float o = v + g.bqkv[c];
            if (c < 256)      g.Q [(long)r*256 + c]       = (bf16)o;
            else if (c < 512) g.Ko[(long)r*256 + (c-256)] = (bf16)o;
            else              g.Vo[(long)r*256 + (c-512)] = o;
          } break;
        }
      }
    }
  }
}

// ===================== fused inner kernel (64m x 128n tiles), R3-style phases =====================
// O = wdc[m]*(A.W^T) + sum_{l-tiles in band} P . B2
// P[m,l] = -(A[m].B1[l]) * exp(cd[m]-cd[l]) * (l<=m) * (ISF2? lr[l]:1)
struct FArgs {
  const bf16 *A, *B1, *B2, *W;
  long sA, sB1, sB2, sW;
  int ldb2;
  const double* cd; long sCd;
  const float* colv; long sColv;
  const float* wdc; long sWdc;
  float* Cf; long sCf;
  bf16* Cb; long sCb;
  int ldc;
};

template<int KSTEPS, int ISF2>
__global__ __launch_bounds__(256)
void fused_inner(FArgs g)
{
  const int m0 = blockIdx.x*64, n0 = blockIdx.y*128, bz = blockIdx.z;
  const int K1 = KSTEPS*32;
  const bf16* A  = g.A  + (long)bz*g.sA;
  const bf16* B1 = g.B1 + (long)bz*g.sB1;
  const bf16* B2 = g.B2 + (long)bz*g.sB2;
  const bf16* W  = g.W  + (long)bz*g.sW;
  const double* cd = g.cd + (long)bz*g.sCd;
  const float* colv = ISF2 ? (g.colv + (long)bz*g.sColv) : (const float*)0;
  const float* wdc = g.wdc + (long)bz*g.sWdc;

  const int tid = threadIdx.x;
  const int lane = tid & 63, w = tid >> 6;
  const int wr = (w>>1)*32, wc = (w&1)*64;
  const int l15 = lane & 15, quad = lane >> 4;
  const int rowA = tid >> 2, kA = (tid & 3) * 8;    // 64x32 A tile, 8 elems/thr
  const int mst = tid >> 1, kst = (tid & 1) * 16;   // 128x32 B tile, 16 elems/thr

  __shared__ __align__(16) bf16 As[64*SA];
  __shared__ __align__(16) bf16 Bs[128*SA];
  __shared__ __align__(16) bf16 Ps[64*SP];

  f32x4 O[2][4];
  #pragma unroll
  for (int i=0;i<2;i++)
    #pragma unroll
    for (int j=0;j<4;j++)
      #pragma unroll
      for (int r=0;r<4;r++) O[i][j][r] = 0.f;

  // ---- init: O = A . W^T
  for (int ks=0; ks<KSTEPS; ks++){
    const int k0 = ks*32;
    *(bf16x8*)&As[rowA*SA + kA] = *(const bf16x8*)(A + (long)(m0+rowA)*K1 + k0 + kA);
    {
      const bf16* src = W + (long)(n0+mst)*K1 + k0 + kst;
      *(bf16x8*)&Bs[mst*SA + kst]     = *(const bf16x8*)(src);
      *(bf16x8*)&Bs[mst*SA + kst + 8] = *(const bf16x8*)(src + 8);
    }
    __syncthreads();
    bf16x8 af[2], bfr[4];
    #pragma unroll
    for (int i=0;i<2;i++) af[i]  = *(const bf16x8*)&As[(wr + i*16 + l15)*SA + quad*8];
    #pragma unroll
    for (int j=0;j<4;j++) bfr[j] = *(const bf16x8*)&Bs[(wc + j*16 + l15)*SA + quad*8];
    #pragma unroll
    for (int i=0;i<2;i++)
      #pragma unroll
      for (int j=0;j<4;j++)
        O[i][j] = __builtin_amdgcn_mfma_f32_16x16x32_bf16(af[i], bfr[j], O[i][j], 0, 0, 0);
    __syncthreads();
  }
  // scale cross term by wdc[m]
  #pragma unroll
  for (int i=0;i<2;i++)
    #pragma unroll
    for (int reg=0; reg<4; reg++){
      const float s = wdc[m0 + wr + i*16 + quad*4 + reg];
      #pragma unroll
      for (int j=0;j<4;j++) O[i][j][reg] *= s;
    }

  // ---- banded l-loop
  int lb = 0;
  while (lb + 128 <= m0 && (cd[m0] - cd[lb+127]) < -45.0) lb += 128;

  for (int l0 = lb; l0 <= m0; l0 += 128) {
    f32x4 P[2][4];
    #pragma unroll
    for (int i=0;i<2;i++)
      #pragma unroll
      for (int j=0;j<4;j++)
        #pragma unroll
        for (int r=0;r<4;r++) P[i][j][r] = 0.f;

    // QK phase: B1 rows l0..l0+127
    for (int ks=0; ks<KSTEPS; ks++){
      const int k0 = ks*32;
      *(bf16x8*)&As[rowA*SA + kA] = *(const bf16x8*)(A + (long)(m0+rowA)*K1 + k0 + kA);
      {
        const bf16* src = B1 + (long)(l0+mst)*K1 + k0 + kst;
        *(bf16x8*)&Bs[mst*SA + kst]     = *(const bf16x8*)(src);
        *(bf16x8*)&Bs[mst*SA + kst + 8] = *(const bf16x8*)(src + 8);
      }
      __syncthreads();
      bf16x8 af[2], bfr[4];
      #pragma unroll
      for (int i=0;i<2;i++) af[i]  = *(const bf16x8*)&As[(wr + i*16 + l15)*SA + quad*8];
      #pragma unroll
      for (int j=0;j<4;j++) bfr[j] = *(const bf16x8*)&Bs[(wc + j*16 + l15)*SA + quad*8];
      #pragma unroll
      for (int i=0;i<2;i++)
        #pragma unroll
        for (int j=0;j<4;j++)
          P[i][j] = __builtin_amdgcn_mfma_f32_16x16x32_bf16(af[i], bfr[j], P[i][j], 0, 0, 0);
      __syncthreads();
    }

    // decay mask -> Ps
    {
      float cl[4], lrv[4];
      #pragma unroll
      for (int j=0;j<4;j++){
        const int l = l0 + wc + j*16 + l15;
        cl[j] = (float)cd[l];
        if (ISF2) lrv[j] = colv[l];
      }
      #pragma unroll
      for (int i=0;i<2;i++)
        #pragma unroll
        for (int reg=0; reg<4; reg++){
          const int mloc = wr + i*16 + quad*4 + reg;
          const int m = m0 + mloc;
          const float cm2 = (float)cd[m];
          #pragma unroll
          for (int j=0;j<4;j++){
            const int lloc = wc + j*16 + l15;
            const int l = l0 + lloc;
            float v = -P[i][j][reg] * __expf(cm2 - cl[j]);
            if (ISF2) v *= lrv[j];
            if (l > m) v = 0.f;
            Ps[mloc*SP + lloc] = (bf16)v;
          }
        }
    }
    __syncthreads();

    // PV phase: O += Ps . B2-tile (B2 rows n0..n0+127, k from l0)
    for (int ks2=0; ks2<4; ks2++){
      {
        const bf16* src = B2 + (long)(n0+mst)*g.ldb2 + l0 + ks2*32 + kst;
        *(bf16x8*)&Bs[mst*SA + kst]     = *(const bf16x8*)(src);
        *(bf16x8*)&Bs[mst*SA + kst + 8] = *(const bf16x8*)(src + 8);
      }
      __syncthreads();
      bf16x8 af[2], bfr[4];
      #pragma unroll
      for (int i=0;i<2;i++) af[i]  = *(const bf16x8*)&Ps[(wr + i*16 + l15)*SP + ks2*32 + quad*8];
      #pragma unroll
      for (int j=0;j<4;j++) bfr[j] = *(const bf16x8*)&Bs[(wc + j*16 + l15)*SA + quad*8];
      #pragma unroll
      for (int i=0;i<2;i++)
        #pragma unroll
        for (int j=0;j<4;j++)
          O[i][j] = __builtin_amdgcn_mfma_f32_16x16x32_bf16(af[i], bfr[j], O[i][j], 0, 0, 0);
      __syncthreads();
    }
  }

  // ---- epilogue
  #pragma unroll
  for (int i=0;i<2;i++){
    const int rb = m0 + wr + i*16 + quad*4;
    #pragma unroll
    for (int j=0;j<4;j++){
      const int c = n0 + wc + j*16 + l15;
      #pragma unroll
      for (int reg=0; reg<4; reg++){
        const long co = (long)(rb+reg)*g.ldc + c;
        if (ISF2) g.Cf[(long)bz*g.sCf + co] = O[i][j][reg];
        else      g.Cb[(long)bz*g.sCb + co] = (bf16)silu_f(O[i][j][reg]);
      }
    }
  }
}

// ===================== helpers =====================
__global__ __launch_bounds__(256)
void transpose_bf16(const bf16* __restrict__ in, bf16* __restrict__ out,
                    int R, int C, long sIn, long sOut)
{
  __shared__ bf16 t[64][72];
  const bf16* ip = in + (long)blockIdx.z*sIn;
  bf16* op = out + (long)blockIdx.z*sOut;
  const int r0 = blockIdx.x*64, c0 = blockIdx.y*64;
  const int tid = threadIdx.x;
  const int lr_ = tid>>2, lc = (tid&3)*16;
  bf16x8 a = *(const bf16x8*)&ip[(long)(r0+lr_)*C + c0+lc];
  bf16x8 b = *(const bf16x8*)&ip[(long)(r0+lr_)*C + c0+lc+8];
  #pragma unroll
  for (int i=0;i<8;i++){ t[lr_][lc+i] = a[i]; t[lr_][lc+8+i] = b[i]; }
  __syncthreads();
  const int oc = tid>>2, orr = (tid&3)*16;
  bf16x8 u, v;
  #pragma unroll
  for (int i=0;i<8;i++){ u[i] = t[orr+i][oc]; v[i] = t[orr+8+i][oc]; }
  *(bf16x8*)&op[(long)(c0+oc)*R + r0+orr]     = u;
  *(bf16x8*)&op[(long)(c0+oc)*R + r0+orr+8]   = v;
}

__global__ __launch_bounds__(256)
void transpose_f32_bf16(const float* __restrict__ in, bf16* __restrict__ out,
                        int R, int C, long sIn, long sOut)
{
  __shared__ bf16 t[64][72];
  const float* ip = in + (long)blockIdx.z*sIn;
  bf16* op = out + (long)blockIdx.z*sOut;
  const int r0 = blockIdx.x*64, c0 = blockIdx.y*64;
  const int tid = threadIdx.x;
  const int lr_ = tid>>2, lc = (tid&3)*16;
  #pragma unroll
  for (int q=0;q<4;q++){
    float4 a = *(const float4*)&ip[(long)(r0+lr_)*C + c0+lc + q*4];
    t[lr_][lc+q*4+0] = (bf16)a.x; t[lr_][lc+q*4+1] = (bf16)a.y;
    t[lr_][lc+q*4+2] = (bf16)a.z; t[lr_][lc+q*4+3] = (bf16)a.w;
  }
  __syncthreads();
  const int oc = tid>>2, orr = (tid&3)*16;
  bf16x8 u, v;
  #pragma unroll
  for (int i=0;i<8;i++){ u[i] = t[orr+i][oc]; v[i] = t[orr+8+i][oc]; }
  *(bf16x8*)&op[(long)(c0+oc)*R + r0+orr]   = u;
  *(bf16x8*)&op[(long)(c0+oc)*R + r0+orr+8] = v;
}

__global__ __launch_bounds__(256)
void conv_f32_bf16(const float* __restrict__ in, bf16* __restrict__ out, long n)
{
  long i = ((long)blockIdx.x*256 + threadIdx.x)*8;
  if (i >= n) return;
  float4 a = *(const float4*)&in[i];
  float4 b = *(const float4*)&in[i+4];
  bf16x8 o;
  o[0]=(bf16)a.x; o[1]=(bf16)a.y; o[2]=(bf16)a.z; o[3]=(bf16)a.w;
  o[4]=(bf16)b.x; o[5]=(bf16)b.y; o[6]=(bf16)b.z; o[7]=(bf16)b.w;
  *(bf16x8*)&out[i] = o;
}

__global__ void concat_bias(const float* __restrict__ bq, const float* __restrict__ bk,
                            const float* __restrict__ bv, float* __restrict__ o)
{
  int t = threadIdx.x;
  o[t] = (t<256) ? bq[t] : ((t<512) ? bk[t-256] : bv[t-512]);
}

__global__ __launch_bounds__(256)
void scalar_proj_kernel(const float* __restrict__ x,
                        const float* __restrict__ wlr, const float* __restrict__ blr,
                        const float* __restrict__ wwd, const float* __restrict__ bwd,
                        const float* __restrict__ lbl, const float* __restrict__ lbw,
                        float* __restrict__ lr, float* __restrict__ lw)
{
  const int row  = blockIdx.x*4 + (threadIdx.x >> 6);
  const int lane = threadIdx.x & 63;
  const float4 a = ((const float4*)(x + (long)row*256))[lane];
  const float4 u = ((const float4*)wlr)[lane];
  const float4 w = ((const float4*)wwd)[lane];
  float d1 = a.x*u.x + a.y*u.y + a.z*u.z + a.w*u.w;
  float d2 = a.x*w.x + a.y*w.y + a.z*w.z + a.w*w.w;
  #pragma unroll
  for (int off=32; off; off>>=1) {
    d1 += __shfl_down(d1, off);
    d2 += __shfl_down(d2, off);
  }
  if (lane == 0) {
    float s1 = 1.f/(1.f+expf(-(d1 + blr[0])));
    lr[row] = expf(lbl[0]) * s1;
    float s2 = 1.f/(1.f+expf(-(d2 + bwd[0])));
    lw[row] = logf(1.f - expf(lbw[0]) * s2);
  }
}

__global__ __launch_bounds__(256)
void cumsum_kernel(const float* __restrict__ lw, const float* __restrict__ lr,
                   double* __restrict__ cd, float* __restrict__ wdc,
                   float* __restrict__ se1, float* __restrict__ se2, int L)
{
  const int b = blockIdx.x;
  const int t = threadIdx.x;
  const float* lwb = lw + (long)b*L;
  __shared__ double sum_s[256];
  double loc[8];
  double s = 0.0;
  #pragma unroll
  for (int i=0;i<8;i++){ s += (double)lwb[t*8+i]; loc[i] = s; }
  sum_s[t] = s;
  __syncthreads();
  for (int off=1; off<256; off<<=1){
    double v = 0.0;
    if (t >= off) v = sum_s[t-off];
    __syncthreads();
    sum_s[t] += v;
    __syncthreads();
  }
  const double prefix = (t > 0) ? sum_s[t-1] : 0.0;
  const double total  = sum_s[255];
  #pragma unroll
  for (int i=0;i<8;i++){
    double c = prefix + loc[i];
    long idx = (long)b*L + t*8 + i;
    cd[idx]  = c;
    wdc[idx] = (float)exp(c);
    double e = exp(total - c);
    se1[idx] = (float)(-e);
    se2[idx] = (float)(-e) * lr[idx];
  }
}

extern "C" void kernel_launch(void* const* d_in, const int* in_sizes, int n_in,
                              void* d_out, int out_size, void* d_ws, size_t ws_size,
                              hipStream_t stream)
{
  const int Bn = 4, L = 2048, D = 256, H = 512;
  const long LD = (long)L*D, LH = (long)L*H, HD = (long)H*D;

  const float* x   = (const float*)d_in[0];
  const float* W1  = (const float*)d_in[1];
  const float* W2  = (const float*)d_in[2];
  const float* Wq  = (const float*)d_in[3];
  const float* bq  = (const float*)d_in[4];
  const float* Wk  = (const float*)d_in[5];
  const float* bk  = (const float*)d_in[6];
  const float* Wv  = (const float*)d_in[7];
  const float* bv  = (const float*)d_in[8];
  const float* wlr = (const float*)d_in[9];
  const float* blr = (const float*)d_in[10];
  const float* wwd = (const float*)d_in[11];
  const float* bwd = (const float*)d_in[12];
  const float* lbl = (const float*)d_in[13];
  const float* lbw = (const float*)d_in[14];
  (void)in_sizes; (void)n_in; (void)out_size; (void)ws_size;

  float* out0 = (float*)d_out;            // Z2_      [B,L,D]
  float* out1 = out0 + (long)Bn*LD;       // W1_next  [B,H,D]
  float* out2 = out1 + (long)Bn*HD;       // W2_next  [B,D,H]

  char* wsp = (char*)d_ws;
  size_t off = 0;
  auto alloc = [&](size_t bytes)->void*{
    void* p = wsp + off; off += (bytes + 255) & ~(size_t)255; return p;
  };
  bf16* xb    = (bf16*)alloc((size_t)Bn*LD*2);
  bf16* Wqkvt = (bf16*)alloc((size_t)3*D*D*2);
  float* bqkv = (float*)alloc((size_t)3*D*4);
  bf16* W1b  = (bf16*)alloc((size_t)Bn*HD*2);
  bf16* W2b  = (bf16*)alloc((size_t)Bn*HD*2);
  bf16* W2t  = (bf16*)alloc((size_t)Bn*HD*2);
  bf16* Qb   = (bf16*)alloc((size_t)Bn*LD*2);
  bf16* Kb   = (bf16*)alloc((size_t)Bn*LD*2);
  bf16* Kt   = (bf16*)alloc((size_t)Bn*LD*2);
  float* Vf  = (float*)alloc((size_t)Bn*LD*4);
  bf16* Z1b  = (bf16*)alloc((size_t)Bn*LH*2);
  bf16* X2b  = (bf16*)alloc((size_t)Bn*LH*2);
  bf16* X2t  = (bf16*)alloc((size_t)Bn*LH*2);
  bf16* gZb  = (bf16*)alloc((size_t)Bn*LD*2);
  bf16* gZt  = (bf16*)alloc((size_t)Bn*LD*2);
  bf16* A1b  = (bf16*)alloc((size_t)Bn*LH*2);
  bf16* A1t  = (bf16*)alloc((size_t)Bn*LH*2);
  bf16* X2_b = (bf16*)alloc((size_t)Bn*LH*2);
  float* lrb = (float*)alloc((size_t)Bn*L*4);
  float* lwb = (float*)alloc((size_t)Bn*L*4);
  float* wdc = (float*)alloc((size_t)Bn*L*4);
  float* se1 = (float*)alloc((size_t)Bn*L*4);
  float* se2 = (float*)alloc((size_t)Bn*L*4);
  double* cdb = (double*)alloc((size_t)Bn*L*8);

  auto run = [&](const MArgs& g, int Z){
    dim3 grid(g.M/128, g.N/64, Z);
    mfma_gemm<<<grid, 256, 0, stream>>>(g);
  };

  // ---- converts / weight transposes
  conv_f32_bf16<<<dim3((Bn*LD)/8/256), 256, 0, stream>>>(x,  xb,  Bn*LD);
  conv_f32_bf16<<<dim3((Bn*HD)/8/256), 256, 0, stream>>>(W1, W1b, Bn*HD);
  conv_f32_bf16<<<dim3((Bn*HD)/8/256), 256, 0, stream>>>(W2, W2b, Bn*HD);
  transpose_f32_bf16<<<dim3(4,4,1), 256, 0, stream>>>(Wq, Wqkvt,         D, D, 0, 0);
  transpose_f32_bf16<<<dim3(4,4,1), 256, 0, stream>>>(Wk, Wqkvt + D*D,   D, D, 0, 0);
  transpose_f32_bf16<<<dim3(4,4,1), 256, 0, stream>>>(Wv, Wqkvt + 2*D*D, D, D, 0, 0);
  transpose_f32_bf16<<<dim3(4,8,Bn), 256, 0, stream>>>(W2, W2t, D, H, HD, HD);
  concat_bias<<<dim3(1), 768, 0, stream>>>(bq, bk, bv, bqkv);

  // ---- scalars
  scalar_proj_kernel<<<dim3(Bn*L/4), 256, 0, stream>>>(x, wlr, blr, wwd, bwd, lbl, lbw, lrb, lwb);
  cumsum_kernel<<<dim3(Bn), 256, 0, stream>>>(lwb, lrb, cdb, wdc, se1, se2, L);

  // ---- fused QKV (M = B*L, N = 768)
  {
    MArgs g{}; g.A = xb; g.lda = D; g.B = Wqkvt; g.ldb = D;
    g.M = Bn*L; g.N = 3*D; g.K = D; g.mode = 11; g.ldc = 0;
    g.Q = Qb; g.Ko = Kb; g.Vo = Vf; g.bqkv = bqkv;
    run(g, 1);
  }
  transpose_bf16<<<dim3(32,4,Bn), 256, 0, stream>>>(Kb, Kt, L, D, LD, LD);

  // ---- Z1 = K.W1^T ; X2 = silu(Z1)
  {
    MArgs g{}; g.A = Kb; g.lda = D; g.sA = LD; g.B = W1b; g.ldb = D; g.sB = HD;
    g.M = L; g.N = H; g.K = D; g.mode = 1; g.ldc = H;
    g.Cb = Z1b; g.sCb = LH; g.Cb2 = X2b; g.sCb2 = LH; run(g, Bn);
  }
  transpose_bf16<<<dim3(32,8,Bn), 256, 0, stream>>>(X2b, X2t, L, H, LH, LH);

  // ---- gZ2 = X2.W2^T - V
  {
    MArgs g{}; g.A = X2b; g.lda = H; g.sA = LH; g.B = W2b; g.ldb = H; g.sB = HD;
    g.M = L; g.N = D; g.K = H; g.mode = 2; g.ldc = D;
    g.auxf = Vf; g.ldax = D; g.sAuxf = LD; g.Cb = gZb; g.sCb = LD; run(g, Bn);
  }
  transpose_bf16<<<dim3(32,4,Bn), 256, 0, stream>>>(gZb, gZt, L, D, LD, LD);

  // ---- A1 = silu_bwd(Z1)*(gZ2.W2)*lr
  {
    MArgs g{}; g.A = gZb; g.lda = D; g.sA = LD; g.B = W2t; g.ldb = D; g.sB = HD;
    g.M = L; g.N = H; g.K = D; g.mode = 3; g.ldc = H;
    g.auxb = Z1b; g.ldax = H; g.sAuxb = LH; g.rowv = lrb; g.sRowv = L;
    g.Cb = A1b; g.sCb = LH; run(g, Bn);
  }
  transpose_bf16<<<dim3(32,8,Bn), 256, 0, stream>>>(A1b, A1t, L, H, LH, LH);

  // ---- F1: X2_ = silu( wdc[m]*(Q.W1^T) + sum_l P1.A1 )
  {
    FArgs f{};
    f.A = Qb;  f.sA = LD;  f.B1 = Kb;  f.sB1 = LD;
    f.B2 = A1t; f.sB2 = LH; f.ldb2 = L;
    f.W = W1b; f.sW = HD;
    f.cd = cdb; f.sCd = L; f.wdc = wdc; f.sWdc = L;
    f.Cb = X2_b; f.sCb = LH; f.ldc = H;
    fused_inner<8,0><<<dim3(L/64, H/128, Bn), 256, 0, stream>>>(f);
  }
  // ---- F2: out0 = wdc[m]*(X2_.W2^T) + sum_l P2.gZ2
  {
    FArgs f{};
    f.A = X2_b; f.sA = LH; f.B1 = X2b; f.sB1 = LH;
    f.B2 = gZt; f.sB2 = LD; f.ldb2 = L;
    f.W = W2b; f.sW = HD;
    f.cd = cdb; f.sCd = L; f.colv = lrb; f.sColv = L; f.wdc = wdc; f.sWdc = L;
    f.Cf = out0; f.sCf = LD; f.ldc = D;
    fused_inner<16,1><<<dim3(L/64, D/128, Bn), 256, 0, stream>>>(f);
  }
  // ---- W1_next = (A1t * se1) . Kt^T + W1*wdc[L-1]
  {
    MArgs g{}; g.A = A1t; g.lda = L; g.sA = LH; g.B = Kt; g.ldb = L; g.sB = LD;
    g.M = H; g.N = D; g.K = L; g.mode = 10; g.ldc = D;
    g.ks = se1; g.sKs = L; g.cd = cdb; g.sCd = L;
    g.auxf = W1; g.ldax = D; g.sAuxf = HD; g.clp = wdc + (L-1); g.sClp = L;
    g.Cf = out1; g.sCf = HD; run(g, Bn);
  }
  // ---- W2_next = (gZt * se2) . X2t^T + W2*wdc[L-1]
  {
    MArgs g{}; g.A = gZt; g.lda = L; g.sA = LD; g.B = X2t; g.ldb = L; g.sB = LH;
    g.M = D; g.N = H; g.K = L; g.mode = 10; g.ldc = H;
    g.ks = se2; g.sKs = L; g.cd = cdb; g.sCd = L;
    g.auxf = W2; g.ldax = H; g.sAuxf = HD; g.clp = wdc + (L-1); g.sClp = L;
    g.Cf = out2; g.sCf = HD; run(g, Bn);
  }
}

// Round 7
// 285.781 us; speedup vs baseline: 10.5744x; 1.1770x over previous
//
#include <hip/hip_runtime.h>

typedef __bf16 bf16;
typedef __bf16 bf16x8 __attribute__((ext_vector_type(8)));
typedef __bf16 bf16x4 __attribute__((ext_vector_type(4)));
typedef float  f32x4  __attribute__((ext_vector_type(4)));

#define SB 72    // LDS row stride (elems) for 64-wide k tiles (16B-aligned, low conflict)
#define SP 136   // LDS row stride (elems) for Ps (128 wide)

__device__ __forceinline__ float silu_f(float x){
  float s = 1.f/(1.f+__expf(-x));
  return x*s;
}
__device__ __forceinline__ float silu_bwd_f(float x){
  float s = 1.f/(1.f+__expf(-x));
  float si = x*s;
  return si + s*(1.f-si);
}

// ===================== generic 128x64 MFMA GEMM (NT), BK=64 =====================
struct MArgs {
  const bf16* A; const bf16* B;
  long sA, sB;
  int lda, ldb;
  int M, N, K;
  int mode;
  float* Cf; long sCf;
  bf16*  Cb; long sCb;
  bf16*  Cb2; long sCb2;
  bf16*  Ct;  long sCt;  int ldct;   // optional transposed output [N][M] (bf16x4 row-chunks)
  int ldc;
  const float* auxf; int ldax; long sAuxf;
  const bf16*  auxb; long sAuxb;
  const float* rowv; long sRowv;
  const double* cd;  long sCd;
  const float* ks;   long sKs;
  const float* clp;  long sClp;
  bf16* Q; bf16* Ko; float* Vo; const float* bqkv;   // mode 11
};

// modes: 1 Cb=acc, Cb2=silu(acc), Ct=silu(acc)^T
//        2 Cb=acc-auxf[r,c], Ct same^T
//        3 Cb=silu_bwd(auxb[r,c])*acc*rowv[r], Ct same^T
//        10 Cf=acc+auxf[r,c]*clv (A scaled by ks[k], dead k-prefix skipped)
//        11 QKV: c<256->Q, <512->Ko (+Ct=Kt), else->Vo (+bias)
__device__ __forceinline__ void gemm_body(const MArgs& g, int bm, int bn, int bz)
{
  const int row0 = bm*128, col0 = bn*64;

  const bf16* A = g.A + (long)bz*g.sA;
  const bf16* B = g.B + (long)bz*g.sB;
  const float* ksp = g.ks ? g.ks + (long)bz*g.sKs : (const float*)0;
  const double* cd = g.cd ? g.cd + (long)bz*g.sCd : (const double*)0;
  float* Cf = g.Cf ? g.Cf + (long)bz*g.sCf : (float*)0;
  bf16* Cb  = g.Cb ? g.Cb + (long)bz*g.sCb : (bf16*)0;
  bf16* Cb2 = g.Cb2 ? g.Cb2 + (long)bz*g.sCb2 : (bf16*)0;
  bf16* Ct  = g.Ct ? g.Ct + (long)bz*g.sCt : (bf16*)0;
  const float* auxf = g.auxf ? g.auxf + (long)bz*g.sAuxf : (const float*)0;
  const bf16*  auxb = g.auxb ? g.auxb + (long)bz*g.sAuxb : (const bf16*)0;
  const float* rowv = g.rowv ? g.rowv + (long)bz*g.sRowv : (const float*)0;

  const int tid = threadIdx.x;
  const int mode = g.mode;
  const int lane = tid & 63;
  const int w = tid >> 6;
  const int wr = (w >> 1) * 64, wc = (w & 1) * 32;
  const int l15 = lane & 15;
  const int quad = lane >> 4;

  __shared__ __align__(16) bf16 As[128*SB];
  __shared__ __align__(16) bf16 Bs[64*SB];

  f32x4 acc[4][2];
  #pragma unroll
  for (int i=0;i<4;i++)
    #pragma unroll
    for (int j=0;j<2;j++)
      #pragma unroll
      for (int r=0;r<4;r++) acc[i][j][r] = 0.f;

  const int rowA = tid >> 1, kA = (tid & 1) * 32;   // 128 rows, 32 elems/thr
  const int rowB = tid >> 2, kB = (tid & 3) * 16;   // 64 rows, 16 elems/thr

  int klo = 0;
  if (cd && ksp) {
    const double cref = cd[g.K-1];
    while (klo + 64 < g.K && (cref - cd[klo+63]) < -45.0) klo += 64;
  }

  for (int k0 = klo; k0 < g.K; k0 += 64) {
    {
      const bf16* s = A + (long)(row0+rowA)*g.lda + k0 + kA;
      bf16x8 v[4];
      #pragma unroll
      for (int p=0;p<4;p++) v[p] = *(const bf16x8*)(s + p*8);
      if (ksp) {
        #pragma unroll
        for (int p=0;p<4;p++)
          #pragma unroll
          for (int i=0;i<8;i++)
            v[p][i] = (bf16)((float)v[p][i] * ksp[k0+kA+p*8+i]);
      }
      #pragma unroll
      for (int p=0;p<4;p++) *(bf16x8*)&As[rowA*SB + kA + p*8] = v[p];
    }
    {
      const bf16* s = B + (long)(col0+rowB)*g.ldb + k0 + kB;
      *(bf16x8*)&Bs[rowB*SB + kB]     = *(const bf16x8*)s;
      *(bf16x8*)&Bs[rowB*SB + kB + 8] = *(const bf16x8*)(s+8);
    }
    __syncthreads();
    #pragma unroll
    for (int ch=0; ch<2; ch++){
      bf16x8 af[4], bf2[2];
      #pragma unroll
      for (int i=0;i<4;i++) af[i]  = *(const bf16x8*)&As[(wr + i*16 + l15)*SB + ch*32 + quad*8];
      #pragma unroll
      for (int j=0;j<2;j++) bf2[j] = *(const bf16x8*)&Bs[(wc + j*16 + l15)*SB + ch*32 + quad*8];
      #pragma unroll
      for (int i=0;i<4;i++)
        #pragma unroll
        for (int j=0;j<2;j++)
          acc[i][j] = __builtin_amdgcn_mfma_f32_16x16x32_bf16(af[i], bf2[j], acc[i][j], 0, 0, 0);
    }
    __syncthreads();
  }

  float clv = 0.f;
  if (mode == 10) clv = *(g.clp + (long)bz*g.sClp);

  #pragma unroll
  for (int i=0;i<4;i++){
    const int rb = row0 + wr + i*16 + quad*4;
    #pragma unroll
    for (int j=0;j<2;j++){
      const int c = col0 + wc + j*16 + l15;
      bf16 tv[4]; bool doT = false;
      #pragma unroll
      for (int reg=0; reg<4; reg++){
        const int r = rb + reg;
        float v = acc[i][j][reg];
        const long co = (long)r*g.ldc + c;
        switch (mode) {
          case 1: {
            Cb[co]  = (bf16)v;
            bf16 sv = (bf16)silu_f(v);
            Cb2[co] = sv;
            tv[reg] = sv; doT = true;
          } break;
          case 2: {
            bf16 o = (bf16)(v - auxf[(long)r*g.ldax + c]);
            Cb[co] = o; tv[reg] = o; doT = true;
          } break;
          case 3: {
            bf16 o = (bf16)(silu_bwd_f((float)auxb[(long)r*g.ldax + c]) * v * rowv[r]);
            Cb[co] = o; tv[reg] = o; doT = true;
          } break;
          case 10: {
            Cf[co] = v + auxf[(long)r*g.ldax + c]*clv;
          } break;
          case 11: {
            float o = v + g.bqkv[c];
            if (c < 256)      g.Q [(long)r*256 + c]       = (bf16)o;
            else if (c < 512) { g.Ko[(long)r*256 + (c-256)] = (bf16)o; tv[reg] = (bf16)o; doT = true; }
            else              g.Vo[(long)r*256 + (c-512)] = o;
          } break;
        }
      }
      if (doT && Ct) {
        bf16x4 t4 = { tv[0], tv[1], tv[2], tv[3] };
        if (mode == 11) {
          const int b = rb / g.ldct, l = rb % g.ldct;
          *(bf16x4*)&Ct[(long)b*g.sCt + (long)(c-256)*g.ldct + l] = t4;
        } else {
          *(bf16x4*)&Ct[(long)c*g.ldct + rb] = t4;
        }
      }
    }
  }
}

__global__ __launch_bounds__(256)
void mfma_gemm(MArgs g){ gemm_body(g, blockIdx.x, blockIdx.y, blockIdx.z); }

// dual-job W-next: z<4 -> g1 (batch z), z>=4 -> g2 (batch z-4); oversize grid blocks early-exit
__global__ __launch_bounds__(256)
void wnext_gemm(MArgs g1, MArgs g2){
  const int z = blockIdx.z;
  const MArgs& g = (z < 4) ? g1 : g2;
  const int bz = z & 3;
  if ((int)blockIdx.x*128 >= g.M || (int)blockIdx.y*64 >= g.N) return;
  gemm_body(g, blockIdx.x, blockIdx.y, bz);
}

// ===================== fused inner kernel (64m x 128n tiles), BK=64 =====================
// O = wdc[m]*(A.W^T) + sum_{l-tiles in band} P . B2
// P[m,l] = -(A[m].B1[l]) * exp(cd[m]-cd[l]) * (l<=m) * (ISF2? lr[l]:1)
struct FArgs {
  const bf16 *A, *B1, *B2, *W;
  long sA, sB1, sB2, sW;
  int ldb2;
  const double* cd; long sCd;
  const float* colv; long sColv;
  const float* wdc; long sWdc;
  float* Cf; long sCf;
  bf16* Cb; long sCb;
  int ldc;
};

template<int KS64, int ISF2>
__global__ __launch_bounds__(256)
void fused_inner(FArgs g)
{
  const int m0 = blockIdx.x*64, n0 = blockIdx.y*128, bz = blockIdx.z;
  const int K1 = KS64*64;
  const bf16* A  = g.A  + (long)bz*g.sA;
  const bf16* B1 = g.B1 + (long)bz*g.sB1;
  const bf16* B2 = g.B2 + (long)bz*g.sB2;
  const bf16* W  = g.W  + (long)bz*g.sW;
  const double* cd = g.cd + (long)bz*g.sCd;
  const float* colv = ISF2 ? (g.colv + (long)bz*g.sColv) : (const float*)0;
  const float* wdc = g.wdc + (long)bz*g.sWdc;

  const int tid = threadIdx.x;
  const int lane = tid & 63, w = tid >> 6;
  const int wr = (w>>1)*32, wc = (w&1)*64;
  const int l15 = lane & 15, quad = lane >> 4;
  const int rowA = tid >> 2, kA = (tid & 3) * 16;   // 64 rows, 16 elems/thr
  const int rowB = tid >> 1, kB = (tid & 1) * 32;   // 128 rows, 32 elems/thr

  __shared__ __align__(16) bf16 As[64*SB];
  __shared__ __align__(16) bf16 Bs[128*SB];
  __shared__ __align__(16) bf16 Ps[64*SP];

  f32x4 O[2][4];
  #pragma unroll
  for (int i=0;i<2;i++)
    #pragma unroll
    for (int j=0;j<4;j++)
      #pragma unroll
      for (int r=0;r<4;r++) O[i][j][r] = 0.f;

  // ---- init: O = A . W^T
  for (int ks=0; ks<KS64; ks++){
    const int k0 = ks*64;
    {
      const bf16* s = A + (long)(m0+rowA)*K1 + k0 + kA;
      *(bf16x8*)&As[rowA*SB + kA]     = *(const bf16x8*)s;
      *(bf16x8*)&As[rowA*SB + kA + 8] = *(const bf16x8*)(s+8);
    }
    {
      const bf16* s = W + (long)(n0+rowB)*K1 + k0 + kB;
      #pragma unroll
      for (int p=0;p<4;p++) *(bf16x8*)&Bs[rowB*SB + kB + p*8] = *(const bf16x8*)(s + p*8);
    }
    __syncthreads();
    #pragma unroll
    for (int ch=0; ch<2; ch++){
      bf16x8 af[2], bfr[4];
      #pragma unroll
      for (int i=0;i<2;i++) af[i]  = *(const bf16x8*)&As[(wr + i*16 + l15)*SB + ch*32 + quad*8];
      #pragma unroll
      for (int j=0;j<4;j++) bfr[j] = *(const bf16x8*)&Bs[(wc + j*16 + l15)*SB + ch*32 + quad*8];
      #pragma unroll
      for (int i=0;i<2;i++)
        #pragma unroll
        for (int j=0;j<4;j++)
          O[i][j] = __builtin_amdgcn_mfma_f32_16x16x32_bf16(af[i], bfr[j], O[i][j], 0, 0, 0);
    }
    __syncthreads();
  }
  // scale cross term by wdc[m]
  #pragma unroll
  for (int i=0;i<2;i++)
    #pragma unroll
    for (int reg=0; reg<4; reg++){
      const float s = wdc[m0 + wr + i*16 + quad*4 + reg];
      #pragma unroll
      for (int j=0;j<4;j++) O[i][j][reg] *= s;
    }

  // ---- banded l-loop
  int lb = 0;
  while (lb + 128 <= m0 && (cd[m0] - cd[lb+127]) < -45.0) lb += 128;

  for (int l0 = lb; l0 <= m0; l0 += 128) {
    f32x4 P[2][4];
    #pragma unroll
    for (int i=0;i<2;i++)
      #pragma unroll
      for (int j=0;j<4;j++)
        #pragma unroll
        for (int r=0;r<4;r++) P[i][j][r] = 0.f;

    // QK phase: B1 rows l0..l0+127
    for (int ks=0; ks<KS64; ks++){
      const int k0 = ks*64;
      {
        const bf16* s = A + (long)(m0+rowA)*K1 + k0 + kA;
        *(bf16x8*)&As[rowA*SB + kA]     = *(const bf16x8*)s;
        *(bf16x8*)&As[rowA*SB + kA + 8] = *(const bf16x8*)(s+8);
      }
      {
        const bf16* s = B1 + (long)(l0+rowB)*K1 + k0 + kB;
        #pragma unroll
        for (int p=0;p<4;p++) *(bf16x8*)&Bs[rowB*SB + kB + p*8] = *(const bf16x8*)(s + p*8);
      }
      __syncthreads();
      #pragma unroll
      for (int ch=0; ch<2; ch++){
        bf16x8 af[2], bfr[4];
        #pragma unroll
        for (int i=0;i<2;i++) af[i]  = *(const bf16x8*)&As[(wr + i*16 + l15)*SB + ch*32 + quad*8];
        #pragma unroll
        for (int j=0;j<4;j++) bfr[j] = *(const bf16x8*)&Bs[(wc + j*16 + l15)*SB + ch*32 + quad*8];
        #pragma unroll
        for (int i=0;i<2;i++)
          #pragma unroll
          for (int j=0;j<4;j++)
            P[i][j] = __builtin_amdgcn_mfma_f32_16x16x32_bf16(af[i], bfr[j], P[i][j], 0, 0, 0);
      }
      __syncthreads();
    }

    // decay mask -> Ps
    {
      float cl[4], lrv[4];
      #pragma unroll
      for (int j=0;j<4;j++){
        const int l = l0 + wc + j*16 + l15;
        cl[j] = (float)cd[l];
        if (ISF2) lrv[j] = colv[l];
      }
      #pragma unroll
      for (int i=0;i<2;i++)
        #pragma unroll
        for (int reg=0; reg<4; reg++){
          const int mloc = wr + i*16 + quad*4 + reg;
          const int m = m0 + mloc;
          const float cm2 = (float)cd[m];
          #pragma unroll
          for (int j=0;j<4;j++){
            const int lloc = wc + j*16 + l15;
            const int l = l0 + lloc;
            float v = -P[i][j][reg] * __expf(cm2 - cl[j]);
            if (ISF2) v *= lrv[j];
            if (l > m) v = 0.f;
            Ps[mloc*SP + lloc] = (bf16)v;
          }
        }
    }
    __syncthreads();

    // PV phase: O += Ps . B2-tile (B2 rows n0..n0+127, k from l0), 2 steps of 64
    for (int st=0; st<2; st++){
      {
        const bf16* s = B2 + (long)(n0+rowB)*g.ldb2 + l0 + st*64 + kB;
        #pragma unroll
        for (int p=0;p<4;p++) *(bf16x8*)&Bs[rowB*SB + kB + p*8] = *(const bf16x8*)(s + p*8);
      }
      __syncthreads();
      #pragma unroll
      for (int ch=0; ch<2; ch++){
        bf16x8 af[2], bfr[4];
        #pragma unroll
        for (int i=0;i<2;i++) af[i]  = *(const bf16x8*)&Ps[(wr + i*16 + l15)*SP + st*64 + ch*32 + quad*8];
        #pragma unroll
        for (int j=0;j<4;j++) bfr[j] = *(const bf16x8*)&Bs[(wc + j*16 + l15)*SB + ch*32 + quad*8];
        #pragma unroll
        for (int i=0;i<2;i++)
          #pragma unroll
          for (int j=0;j<4;j++)
            O[i][j] = __builtin_amdgcn_mfma_f32_16x16x32_bf16(af[i], bfr[j], O[i][j], 0, 0, 0);
      }
      __syncthreads();
    }
  }

  // ---- epilogue
  #pragma unroll
  for (int i=0;i<2;i++){
    const int rb = m0 + wr + i*16 + quad*4;
    #pragma unroll
    for (int j=0;j<4;j++){
      const int c = n0 + wc + j*16 + l15;
      #pragma unroll
      for (int reg=0; reg<4; reg++){
        const long co = (long)(rb+reg)*g.ldc + c;
        if (ISF2) g.Cf[(long)bz*g.sCf + co] = O[i][j][reg];
        else      g.Cb[(long)bz*g.sCb + co] = (bf16)silu_f(O[i][j][reg]);
      }
    }
  }
}

// ===================== helpers =====================
// multi-tensor f32->bf16 convert: job = blockIdx.y
__global__ __launch_bounds__(256)
void conv_multi(const float* __restrict__ a, bf16* __restrict__ oa, long na,
                const float* __restrict__ b, bf16* __restrict__ ob, long nb,
                const float* __restrict__ c, bf16* __restrict__ oc, long nc)
{
  const int job = blockIdx.y;
  const float* src = job==0 ? a : (job==1 ? b : c);
  bf16* dst       = job==0 ? oa : (job==1 ? ob : oc);
  const long n    = job==0 ? na : (job==1 ? nb : nc);
  long i = ((long)blockIdx.x*256 + threadIdx.x)*8;
  if (i >= n) return;
  float4 x = *(const float4*)&src[i];
  float4 y = *(const float4*)&src[i+4];
  bf16x8 o;
  o[0]=(bf16)x.x; o[1]=(bf16)x.y; o[2]=(bf16)x.z; o[3]=(bf16)x.w;
  o[4]=(bf16)y.x; o[5]=(bf16)y.y; o[6]=(bf16)y.z; o[7]=(bf16)y.w;
  *(bf16x8*)&dst[i] = o;
}

// Wq/Wk/Wv (256x256 f32) -> transposed bf16 at out + z*65536
__global__ __launch_bounds__(256)
void transpose_qkv(const float* __restrict__ Wq, const float* __restrict__ Wk,
                   const float* __restrict__ Wv, bf16* __restrict__ out)
{
  __shared__ bf16 t[64][72];
  const int z = blockIdx.z;
  const float* ip = z==0 ? Wq : (z==1 ? Wk : Wv);
  bf16* op = out + (long)z*256*256;
  const int r0 = blockIdx.x*64, c0 = blockIdx.y*64;
  const int tid = threadIdx.x;
  const int lr_ = tid>>2, lc = (tid&3)*16;
  #pragma unroll
  for (int q=0;q<4;q++){
    float4 a = *(const float4*)&ip[(long)(r0+lr_)*256 + c0+lc + q*4];
    t[lr_][lc+q*4+0] = (bf16)a.x; t[lr_][lc+q*4+1] = (bf16)a.y;
    t[lr_][lc+q*4+2] = (bf16)a.z; t[lr_][lc+q*4+3] = (bf16)a.w;
  }
  __syncthreads();
  const int oc = tid>>2, orr = (tid&3)*16;
  bf16x8 u, v;
  #pragma unroll
  for (int i=0;i<8;i++){ u[i] = t[orr+i][oc]; v[i] = t[orr+8+i][oc]; }
  *(bf16x8*)&op[(long)(c0+oc)*256 + r0+orr]   = u;
  *(bf16x8*)&op[(long)(c0+oc)*256 + r0+orr+8] = v;
}

__global__ __launch_bounds__(256)
void transpose_f32_bf16(const float* __restrict__ in, bf16* __restrict__ out,
                        int R, int C, long sIn, long sOut)
{
  __shared__ bf16 t[64][72];
  const float* ip = in + (long)blockIdx.z*sIn;
  bf16* op = out + (long)blockIdx.z*sOut;
  const int r0 = blockIdx.x*64, c0 = blockIdx.y*64;
  const int tid = threadIdx.x;
  const int lr_ = tid>>2, lc = (tid&3)*16;
  #pragma unroll
  for (int q=0;q<4;q++){
    float4 a = *(const float4*)&ip[(long)(r0+lr_)*C + c0+lc + q*4];
    t[lr_][lc+q*4+0] = (bf16)a.x; t[lr_][lc+q*4+1] = (bf16)a.y;
    t[lr_][lc+q*4+2] = (bf16)a.z; t[lr_][lc+q*4+3] = (bf16)a.w;
  }
  __syncthreads();
  const int oc = tid>>2, orr = (tid&3)*16;
  bf16x8 u, v;
  #pragma unroll
  for (int i=0;i<8;i++){ u[i] = t[orr+i][oc]; v[i] = t[orr+8+i][oc]; }
  *(bf16x8*)&op[(long)(c0+oc)*R + r0+orr]   = u;
  *(bf16x8*)&op[(long)(c0+oc)*R + r0+orr+8] = v;
}

__global__ __launch_bounds__(256)
void scalar_proj_kernel(const float* __restrict__ x,
                        const float* __restrict__ wlr, const float* __restrict__ blr,
                        const float* __restrict__ wwd, const float* __restrict__ bwd,
                        const float* __restrict__ lbl, const float* __restrict__ lbw,
                        float* __restrict__ lr, float* __restrict__ lw)
{
  const int row  = blockIdx.x*4 + (threadIdx.x >> 6);
  const int lane = threadIdx.x & 63;
  const float4 a = ((const float4*)(x + (long)row*256))[lane];
  const float4 u = ((const float4*)wlr)[lane];
  const float4 w = ((const float4*)wwd)[lane];
  float d1 = a.x*u.x + a.y*u.y + a.z*u.z + a.w*u.w;
  float d2 = a.x*w.x + a.y*w.y + a.z*w.z + a.w*w.w;
  #pragma unroll
  for (int off=32; off; off>>=1) {
    d1 += __shfl_down(d1, off);
    d2 += __shfl_down(d2, off);
  }
  if (lane == 0) {
    float s1 = 1.f/(1.f+expf(-(d1 + blr[0])));
    lr[row] = expf(lbl[0]) * s1;
    float s2 = 1.f/(1.f+expf(-(d2 + bwd[0])));
    lw[row] = logf(1.f - expf(lbw[0]) * s2);
  }
}

// blocks 0..3: per-batch fp64 scan + derived; block 4: bias concat
__global__ __launch_bounds__(256)
void cumsum_kernel(const float* __restrict__ lw, const float* __restrict__ lr,
                   double* __restrict__ cd, float* __restrict__ wdc,
                   float* __restrict__ se1, float* __restrict__ se2, int L,
                   const float* __restrict__ bq, const float* __restrict__ bk,
                   const float* __restrict__ bv, float* __restrict__ bqkv)
{
  const int b = blockIdx.x;
  const int t = threadIdx.x;
  if (b == 4) {
    for (int i = t; i < 768; i += 256)
      bqkv[i] = (i<256) ? bq[i] : ((i<512) ? bk[i-256] : bv[i-512]);
    return;
  }
  const float* lwb = lw + (long)b*L;
  __shared__ double sum_s[256];
  double loc[8];
  double s = 0.0;
  #pragma unroll
  for (int i=0;i<8;i++){ s += (double)lwb[t*8+i]; loc[i] = s; }
  sum_s[t] = s;
  __syncthreads();
  for (int off=1; off<256; off<<=1){
    double v = 0.0;
    if (t >= off) v = sum_s[t-off];
    __syncthreads();
    sum_s[t] += v;
    __syncthreads();
  }
  const double prefix = (t > 0) ? sum_s[t-1] : 0.0;
  const double total  = sum_s[255];
  #pragma unroll
  for (int i=0;i<8;i++){
    double c = prefix + loc[i];
    long idx = (long)b*L + t*8 + i;
    cd[idx]  = c;
    wdc[idx] = (float)exp(c);
    double e = exp(total - c);
    se1[idx] = (float)(-e);
    se2[idx] = (float)(-e) * lr[idx];
  }
}

extern "C" void kernel_launch(void* const* d_in, const int* in_sizes, int n_in,
                              void* d_out, int out_size, void* d_ws, size_t ws_size,
                              hipStream_t stream)
{
  const int Bn = 4, L = 2048, D = 256, H = 512;
  const long LD = (long)L*D, LH = (long)L*H, HD = (long)H*D;

  const float* x   = (const float*)d_in[0];
  const float* W1  = (const float*)d_in[1];
  const float* W2  = (const float*)d_in[2];
  const float* Wq  = (const float*)d_in[3];
  const float* bq  = (const float*)d_in[4];
  const float* Wk  = (const float*)d_in[5];
  const float* bk  = (const float*)d_in[6];
  const float* Wv  = (const float*)d_in[7];
  const float* bv  = (const float*)d_in[8];
  const float* wlr = (const float*)d_in[9];
  const float* blr = (const float*)d_in[10];
  const float* wwd = (const float*)d_in[11];
  const float* bwd = (const float*)d_in[12];
  const float* lbl = (const float*)d_in[13];
  const float* lbw = (const float*)d_in[14];
  (void)in_sizes; (void)n_in; (void)out_size; (void)ws_size;

  float* out0 = (float*)d_out;            // Z2_      [B,L,D]
  float* out1 = out0 + (long)Bn*LD;       // W1_next  [B,H,D]
  float* out2 = out1 + (long)Bn*HD;       // W2_next  [B,D,H]

  char* wsp = (char*)d_ws;
  size_t off = 0;
  auto alloc = [&](size_t bytes)->void*{
    void* p = wsp + off; off += (bytes + 255) & ~(size_t)255; return p;
  };
  bf16* xb    = (bf16*)alloc((size_t)Bn*LD*2);
  bf16* Wqkvt = (bf16*)alloc((size_t)3*D*D*2);
  float* bqkv = (float*)alloc((size_t)3*D*4);
  bf16* W1b  = (bf16*)alloc((size_t)Bn*HD*2);
  bf16* W2b  = (bf16*)alloc((size_t)Bn*HD*2);
  bf16* W2t  = (bf16*)alloc((size_t)Bn*HD*2);
  bf16* Qb   = (bf16*)alloc((size_t)Bn*LD*2);
  bf16* Kb   = (bf16*)alloc((size_t)Bn*LD*2);
  bf16* Kt   = (bf16*)alloc((size_t)Bn*LD*2);
  float* Vf  = (float*)alloc((size_t)Bn*LD*4);
  bf16* Z1b  = (bf16*)alloc((size_t)Bn*LH*2);
  bf16* X2b  = (bf16*)alloc((size_t)Bn*LH*2);
  bf16* X2t  = (bf16*)alloc((size_t)Bn*LH*2);
  bf16* gZb  = (bf16*)alloc((size_t)Bn*LD*2);
  bf16* gZt  = (bf16*)alloc((size_t)Bn*LD*2);
  bf16* A1b  = (bf16*)alloc((size_t)Bn*LH*2);
  bf16* A1t  = (bf16*)alloc((size_t)Bn*LH*2);
  bf16* X2_b = (bf16*)alloc((size_t)Bn*LH*2);
  float* lrb = (float*)alloc((size_t)Bn*L*4);
  float* lwb = (float*)alloc((size_t)Bn*L*4);
  float* wdc = (float*)alloc((size_t)Bn*L*4);
  float* se1 = (float*)alloc((size_t)Bn*L*4);
  float* se2 = (float*)alloc((size_t)Bn*L*4);
  double* cdb = (double*)alloc((size_t)Bn*L*8);

  auto run = [&](const MArgs& g, int Z){
    dim3 grid(g.M/128, g.N/64, Z);
    mfma_gemm<<<grid, 256, 0, stream>>>(g);
  };

  // ---- front matter (merged)
  conv_multi<<<dim3(1024,3), 256, 0, stream>>>(x, xb, Bn*LD, W1, W1b, Bn*HD, W2, W2b, Bn*HD);
  transpose_qkv<<<dim3(4,4,3), 256, 0, stream>>>(Wq, Wk, Wv, Wqkvt);
  transpose_f32_bf16<<<dim3(4,8,Bn), 256, 0, stream>>>(W2, W2t, D, H, HD, HD);
  scalar_proj_kernel<<<dim3(Bn*L/4), 256, 0, stream>>>(x, wlr, blr, wwd, bwd, lbl, lbw, lrb, lwb);
  cumsum_kernel<<<dim3(5), 256, 0, stream>>>(lwb, lrb, cdb, wdc, se1, se2, L, bq, bk, bv, bqkv);

  // ---- fused QKV (M = B*L, N = 768); Kt written via Ct path
  {
    MArgs g{}; g.A = xb; g.lda = D; g.B = Wqkvt; g.ldb = D;
    g.M = Bn*L; g.N = 3*D; g.K = D; g.mode = 11; g.ldc = 0;
    g.Q = Qb; g.Ko = Kb; g.Vo = Vf; g.bqkv = bqkv;
    g.Ct = Kt; g.sCt = LD; g.ldct = L;
    run(g, 1);
  }
  // ---- Z1 = K.W1^T ; X2 = silu(Z1); X2t via Ct
  {
    MArgs g{}; g.A = Kb; g.lda = D; g.sA = LD; g.B = W1b; g.ldb = D; g.sB = HD;
    g.M = L; g.N = H; g.K = D; g.mode = 1; g.ldc = H;
    g.Cb = Z1b; g.sCb = LH; g.Cb2 = X2b; g.sCb2 = LH;
    g.Ct = X2t; g.sCt = LH; g.ldct = L; run(g, Bn);
  }
  // ---- gZ2 = X2.W2^T - V; gZt via Ct
  {
    MArgs g{}; g.A = X2b; g.lda = H; g.sA = LH; g.B = W2b; g.ldb = H; g.sB = HD;
    g.M = L; g.N = D; g.K = H; g.mode = 2; g.ldc = D;
    g.auxf = Vf; g.ldax = D; g.sAuxf = LD; g.Cb = gZb; g.sCb = LD;
    g.Ct = gZt; g.sCt = LD; g.ldct = L; run(g, Bn);
  }
  // ---- A1 = silu_bwd(Z1)*(gZ2.W2)*lr; A1t via Ct
  {
    MArgs g{}; g.A = gZb; g.lda = D; g.sA = LD; g.B = W2t; g.ldb = D; g.sB = HD;
    g.M = L; g.N = H; g.K = D; g.mode = 3; g.ldc = H;
    g.auxb = Z1b; g.ldax = H; g.sAuxb = LH; g.rowv = lrb; g.sRowv = L;
    g.Cb = A1b; g.sCb = LH;
    g.Ct = A1t; g.sCt = LH; g.ldct = L; run(g, Bn);
  }
  // ---- F1: X2_ = silu( wdc[m]*(Q.W1^T) + sum_l P1.A1 )
  {
    FArgs f{};
    f.A = Qb;  f.sA = LD;  f.B1 = Kb;  f.sB1 = LD;
    f.B2 = A1t; f.sB2 = LH; f.ldb2 = L;
    f.W = W1b; f.sW = HD;
    f.cd = cdb; f.sCd = L; f.wdc = wdc; f.sWdc = L;
    f.Cb = X2_b; f.sCb = LH; f.ldc = H;
    fused_inner<4,0><<<dim3(L/64, H/128, Bn), 256, 0, stream>>>(f);
  }
  // ---- F2: out0 = wdc[m]*(X2_.W2^T) + sum_l P2.gZ2
  {
    FArgs f{};
    f.A = X2_b; f.sA = LH; f.B1 = X2b; f.sB1 = LH;
    f.B2 = gZt; f.sB2 = LD; f.ldb2 = L;
    f.W = W2b; f.sW = HD;
    f.cd = cdb; f.sCd = L; f.colv = lrb; f.sColv = L; f.wdc = wdc; f.sWdc = L;
    f.Cf = out0; f.sCf = LD; f.ldc = D;
    fused_inner<8,1><<<dim3(L/64, D/128, Bn), 256, 0, stream>>>(f);
  }
  // ---- W1_next + W2_next in one launch
  {
    MArgs g1{}; g1.A = A1t; g1.lda = L; g1.sA = LH; g1.B = Kt; g1.ldb = L; g1.sB = LD;
    g1.M = H; g1.N = D; g1.K = L; g1.mode = 10; g1.ldc = D;
    g1.ks = se1; g1.sKs = L; g1.cd = cdb; g1.sCd = L;
    g1.auxf = W1; g1.ldax = D; g1.sAuxf = HD; g1.clp = wdc + (L-1); g1.sClp = L;
    g1.Cf = out1; g1.sCf = HD;

    MArgs g2{}; g2.A = gZt; g2.lda = L; g2.sA = LD; g2.B = X2t; g2.ldb = L; g2.sB = LH;
    g2.M = D; g2.N = H; g2.K = L; g2.mode = 10; g2.ldc = H;
    g2.ks = se2; g2.sKs = L; g2.cd = cdb; g2.sCd = L;
    g2.auxf = W2; g2.ldax = H; g2.sAuxf = HD; g2.clp = wdc + (L-1); g2.sClp = L;
    g2.Cf = out2; g2.sCf = HD;

    wnext_gemm<<<dim3(4,8,8), 256, 0, stream>>>(g1, g2);
  }
}

// Round 8
// 250.998 us; speedup vs baseline: 12.0398x; 1.1386x over previous
//
#include <hip/hip_runtime.h>

typedef __bf16 bf16;
typedef __bf16 bf16x8 __attribute__((ext_vector_type(8)));
typedef __bf16 bf16x4 __attribute__((ext_vector_type(4)));
typedef float  f32x4  __attribute__((ext_vector_type(4)));

#define SB 72    // LDS row stride (elems) for 64-wide k tiles
#define SP 136   // LDS row stride (elems) for Ps (128 wide)
#define CUTOFF -25.0

__device__ __forceinline__ float silu_f(float x){
  float s = 1.f/(1.f+__expf(-x));
  return x*s;
}
__device__ __forceinline__ float silu_bwd_f(float x){
  float s = 1.f/(1.f+__expf(-x));
  float si = x*s;
  return si + s*(1.f-si);
}

// ===================== generic TMx64 MFMA GEMM (NT), BK=64 =====================
struct MArgs {
  const bf16* A; const bf16* B;
  long sA, sB;
  int lda, ldb;
  int M, N, K;
  int mode;
  float* Cf; long sCf;
  bf16*  Cb; long sCb;
  bf16*  Cb2; long sCb2;
  bf16*  Ct;  long sCt;  int ldct;   // optional transposed output
  int ldc;
  const float* auxf; int ldax; long sAuxf;
  const bf16*  auxb; long sAuxb;
  const float* rowv; long sRowv;
  const double* cd;  long sCd;
  const float* ks;   long sKs;
  const float* clp;  long sClp;
  bf16* Q; bf16* Ko; float* Vo; const float* bqkv;   // mode 11
};

// modes: 1 Cb=acc, Cb2=silu(acc), Ct=silu(acc)^T
//        2 Cb=acc-auxf[r,c], Ct same^T
//        3 Cb=silu_bwd(auxb[r,c])*acc*rowv[r], Ct same^T
//        10 Cf=acc+auxf[r,c]*clv (A scaled by ks[k], dead k-prefix skipped)
//        11 QKV: c<256->Q, <512->Ko (+Ct=Kt), else->Vo (+bias)
template<int TM>
__device__ __forceinline__ void gemm_body(const MArgs& g, int bm, int bn, int bz)
{
  const int row0 = bm*TM, col0 = bn*64;
  constexpr int NI  = TM/32;       // acc rows per wave-frag loop
  constexpr int TPR = 256/TM;      // threads per A row
  constexpr int EPR = 64/TPR;      // elems per thread (A staging)
  constexpr int NCH = EPR/8;

  const bf16* A = g.A + (long)bz*g.sA;
  const bf16* B = g.B + (long)bz*g.sB;
  const float* ksp = g.ks ? g.ks + (long)bz*g.sKs : (const float*)0;
  const double* cd = g.cd ? g.cd + (long)bz*g.sCd : (const double*)0;
  float* Cf = g.Cf ? g.Cf + (long)bz*g.sCf : (float*)0;
  bf16* Cb  = g.Cb ? g.Cb + (long)bz*g.sCb : (bf16*)0;
  bf16* Cb2 = g.Cb2 ? g.Cb2 + (long)bz*g.sCb2 : (bf16*)0;
  bf16* Ct  = g.Ct ? g.Ct + (long)bz*g.sCt : (bf16*)0;
  const float* auxf = g.auxf ? g.auxf + (long)bz*g.sAuxf : (const float*)0;
  const bf16*  auxb = g.auxb ? g.auxb + (long)bz*g.sAuxb : (const bf16*)0;
  const float* rowv = g.rowv ? g.rowv + (long)bz*g.sRowv : (const float*)0;

  const int tid = threadIdx.x;
  const int mode = g.mode;
  const int lane = tid & 63;
  const int w = tid >> 6;
  const int wr = (w >> 1) * (TM/2), wc = (w & 1) * 32;
  const int l15 = lane & 15;
  const int quad = lane >> 4;

  __shared__ __align__(16) bf16 As[TM*SB];
  __shared__ __align__(16) bf16 Bs[64*SB];

  f32x4 acc[NI][2];
  #pragma unroll
  for (int i=0;i<NI;i++)
    #pragma unroll
    for (int j=0;j<2;j++)
      #pragma unroll
      for (int r=0;r<4;r++) acc[i][j][r] = 0.f;

  const int rowA = tid / TPR, kA = (tid % TPR) * EPR;
  const int rowB = tid >> 2,  kB = (tid & 3) * 16;

  int klo = 0;
  if (cd && ksp) {
    const double cref = cd[g.K-1];
    while (klo + 64 < g.K && (cref - cd[klo+63]) < CUTOFF) klo += 64;
  }

  for (int k0 = klo; k0 < g.K; k0 += 64) {
    {
      const bf16* s = A + (long)(row0+rowA)*g.lda + k0 + kA;
      bf16x8 v[NCH];
      #pragma unroll
      for (int p=0;p<NCH;p++) v[p] = *(const bf16x8*)(s + p*8);
      if (ksp) {
        #pragma unroll
        for (int p=0;p<NCH;p++)
          #pragma unroll
          for (int i=0;i<8;i++)
            v[p][i] = (bf16)((float)v[p][i] * ksp[k0+kA+p*8+i]);
      }
      #pragma unroll
      for (int p=0;p<NCH;p++) *(bf16x8*)&As[rowA*SB + kA + p*8] = v[p];
    }
    {
      const bf16* s = B + (long)(col0+rowB)*g.ldb + k0 + kB;
      *(bf16x8*)&Bs[rowB*SB + kB]     = *(const bf16x8*)s;
      *(bf16x8*)&Bs[rowB*SB + kB + 8] = *(const bf16x8*)(s+8);
    }
    __syncthreads();
    #pragma unroll
    for (int ch=0; ch<2; ch++){
      bf16x8 af[NI], bf2[2];
      #pragma unroll
      for (int i=0;i<NI;i++) af[i]  = *(const bf16x8*)&As[(wr + i*16 + l15)*SB + ch*32 + quad*8];
      #pragma unroll
      for (int j=0;j<2;j++) bf2[j] = *(const bf16x8*)&Bs[(wc + j*16 + l15)*SB + ch*32 + quad*8];
      #pragma unroll
      for (int i=0;i<NI;i++)
        #pragma unroll
        for (int j=0;j<2;j++)
          acc[i][j] = __builtin_amdgcn_mfma_f32_16x16x32_bf16(af[i], bf2[j], acc[i][j], 0, 0, 0);
    }
    __syncthreads();
  }

  float clv = 0.f;
  if (mode == 10) clv = *(g.clp + (long)bz*g.sClp);

  #pragma unroll
  for (int i=0;i<NI;i++){
    const int rb = row0 + wr + i*16 + quad*4;
    #pragma unroll
    for (int j=0;j<2;j++){
      const int c = col0 + wc + j*16 + l15;
      bf16 tv[4]; bool doT = false;
      #pragma unroll
      for (int reg=0; reg<4; reg++){
        const int r = rb + reg;
        float v = acc[i][j][reg];
        const long co = (long)r*g.ldc + c;
        switch (mode) {
          case 1: {
            Cb[co]  = (bf16)v;
            bf16 sv = (bf16)silu_f(v);
            Cb2[co] = sv;
            tv[reg] = sv; doT = true;
          } break;
          case 2: {
            bf16 o = (bf16)(v - auxf[(long)r*g.ldax + c]);
            Cb[co] = o; tv[reg] = o; doT = true;
          } break;
          case 3: {
            bf16 o = (bf16)(silu_bwd_f((float)auxb[(long)r*g.ldax + c]) * v * rowv[r]);
            Cb[co] = o; tv[reg] = o; doT = true;
          } break;
          case 10: {
            Cf[co] = v + auxf[(long)r*g.ldax + c]*clv;
          } break;
          case 11: {
            float o = v + g.bqkv[c];
            if (c < 256)      g.Q [(long)r*256 + c]       = (bf16)o;
            else if (c < 512) { g.Ko[(long)r*256 + (c-256)] = (bf16)o; tv[reg] = (bf16)o; doT = true; }
            else              g.Vo[(long)r*256 + (c-512)] = o;
          } break;
        }
      }
      if (doT && Ct) {
        bf16x4 t4 = { tv[0], tv[1], tv[2], tv[3] };
        if (mode == 11) {
          const int b = rb / g.ldct, l = rb % g.ldct;
          *(bf16x4*)&Ct[(long)b*g.sCt + (long)(c-256)*g.ldct + l] = t4;
        } else {
          *(bf16x4*)&Ct[(long)c*g.ldct + rb] = t4;
        }
      }
    }
  }
}

__global__ __launch_bounds__(256)
void mfma_gemm128(MArgs g){ gemm_body<128>(g, blockIdx.x, blockIdx.y, blockIdx.z); }

__global__ __launch_bounds__(256)
void mfma_gemm64(MArgs g){ gemm_body<64>(g, blockIdx.x, blockIdx.y, blockIdx.z); }

// dual-job W-next: z<4 -> g1 (batch z), z>=4 -> g2 (batch z-4)
__global__ __launch_bounds__(256)
void wnext_gemm(MArgs g1, MArgs g2){
  const int z = blockIdx.z;
  const MArgs& g = (z < 4) ? g1 : g2;
  const int bz = z & 3;
  if ((int)blockIdx.x*128 >= g.M || (int)blockIdx.y*64 >= g.N) return;
  gemm_body<128>(g, blockIdx.x, blockIdx.y, bz);
}

// ===================== fused inner kernel (64m x 128n tiles), BK=64 =====================
// O = wdc[m]*(A.W^T) + sum_{l-tiles in band} P . B2
// P[m,l] = -(A[m].B1[l]) * exp(cd[m]-cd[l]) * (l<=m) * (ISF2? lr[l]:1)
// ZSPLIT: band tiles strided across z-pairs, fp32 atomic accumulation into Cf (pre-zeroed)
struct FArgs {
  const bf16 *A, *B1, *B2, *W;
  long sA, sB1, sB2, sW;
  int ldb2;
  const double* cd; long sCd;
  const float* colv; long sColv;
  const float* wdc; long sWdc;
  float* Cf; long sCf;
  bf16* Cb; long sCb;
  int ldc;
};

template<int KS64, int ISF2, int ZSPLIT>
__global__ __launch_bounds__(256)
void fused_inner(FArgs g)
{
  const int m0 = blockIdx.x*64, n0 = blockIdx.y*128;
  const int bz   = ZSPLIT ? (blockIdx.z >> 1) : blockIdx.z;
  const int half = ZSPLIT ? (blockIdx.z & 1)  : 0;
  const int K1 = KS64*64;
  const bf16* A  = g.A  + (long)bz*g.sA;
  const bf16* B1 = g.B1 + (long)bz*g.sB1;
  const bf16* B2 = g.B2 + (long)bz*g.sB2;
  const bf16* W  = g.W  + (long)bz*g.sW;
  const double* cd = g.cd + (long)bz*g.sCd;
  const float* colv = ISF2 ? (g.colv + (long)bz*g.sColv) : (const float*)0;
  const float* wdc = g.wdc + (long)bz*g.sWdc;

  // band start
  int lb = 0;
  while (lb + 128 <= m0 && (cd[m0] - cd[lb+127]) < CUTOFF) lb += 128;
  // half 1 with no tiles: nothing to contribute
  if (ZSPLIT && half == 1 && lb + 128 > m0) return;

  const int tid = threadIdx.x;
  const int lane = tid & 63, w = tid >> 6;
  const int wr = (w>>1)*32, wc = (w&1)*64;
  const int l15 = lane & 15, quad = lane >> 4;
  const int rowA = tid >> 2, kA = (tid & 3) * 16;   // 64 rows, 16 elems/thr
  const int rowB = tid >> 1, kB = (tid & 1) * 32;   // 128 rows, 32 elems/thr

  __shared__ __align__(16) bf16 As[64*SB];
  __shared__ __align__(16) bf16 Bs[128*SB];
  __shared__ __align__(16) bf16 Ps[64*SP];

  f32x4 O[2][4];
  #pragma unroll
  for (int i=0;i<2;i++)
    #pragma unroll
    for (int j=0;j<4;j++)
      #pragma unroll
      for (int r=0;r<4;r++) O[i][j][r] = 0.f;

  // ---- init: O = wdc[m] * (A . W^T)   (half 0 only)
  if (half == 0) {
    for (int ks=0; ks<KS64; ks++){
      const int k0 = ks*64;
      {
        const bf16* s = A + (long)(m0+rowA)*K1 + k0 + kA;
        *(bf16x8*)&As[rowA*SB + kA]     = *(const bf16x8*)s;
        *(bf16x8*)&As[rowA*SB + kA + 8] = *(const bf16x8*)(s+8);
      }
      {
        const bf16* s = W + (long)(n0+rowB)*K1 + k0 + kB;
        #pragma unroll
        for (int p=0;p<4;p++) *(bf16x8*)&Bs[rowB*SB + kB + p*8] = *(const bf16x8*)(s + p*8);
      }
      __syncthreads();
      #pragma unroll
      for (int ch=0; ch<2; ch++){
        bf16x8 af[2], bfr[4];
        #pragma unroll
        for (int i=0;i<2;i++) af[i]  = *(const bf16x8*)&As[(wr + i*16 + l15)*SB + ch*32 + quad*8];
        #pragma unroll
        for (int j=0;j<4;j++) bfr[j] = *(const bf16x8*)&Bs[(wc + j*16 + l15)*SB + ch*32 + quad*8];
        #pragma unroll
        for (int i=0;i<2;i++)
          #pragma unroll
          for (int j=0;j<4;j++)
            O[i][j] = __builtin_amdgcn_mfma_f32_16x16x32_bf16(af[i], bfr[j], O[i][j], 0, 0, 0);
      }
      __syncthreads();
    }
    #pragma unroll
    for (int i=0;i<2;i++)
      #pragma unroll
      for (int reg=0; reg<4; reg++){
        const float s = wdc[m0 + wr + i*16 + quad*4 + reg];
        #pragma unroll
        for (int j=0;j<4;j++) O[i][j][reg] *= s;
      }
  }

  // ---- banded l-loop (strided across halves when ZSPLIT)
  const int lstep = ZSPLIT ? 256 : 128;
  for (int l0 = lb + half*128; l0 <= m0; l0 += lstep) {
    f32x4 P[2][4];
    #pragma unroll
    for (int i=0;i<2;i++)
      #pragma unroll
      for (int j=0;j<4;j++)
        #pragma unroll
        for (int r=0;r<4;r++) P[i][j][r] = 0.f;

    // QK phase: B1 rows l0..l0+127
    for (int ks=0; ks<KS64; ks++){
      const int k0 = ks*64;
      {
        const bf16* s = A + (long)(m0+rowA)*K1 + k0 + kA;
        *(bf16x8*)&As[rowA*SB + kA]     = *(const bf16x8*)s;
        *(bf16x8*)&As[rowA*SB + kA + 8] = *(const bf16x8*)(s+8);
      }
      {
        const bf16* s = B1 + (long)(l0+rowB)*K1 + k0 + kB;
        #pragma unroll
        for (int p=0;p<4;p++) *(bf16x8*)&Bs[rowB*SB + kB + p*8] = *(const bf16x8*)(s + p*8);
      }
      __syncthreads();
      #pragma unroll
      for (int ch=0; ch<2; ch++){
        bf16x8 af[2], bfr[4];
        #pragma unroll
        for (int i=0;i<2;i++) af[i]  = *(const bf16x8*)&As[(wr + i*16 + l15)*SB + ch*32 + quad*8];
        #pragma unroll
        for (int j=0;j<4;j++) bfr[j] = *(const bf16x8*)&Bs[(wc + j*16 + l15)*SB + ch*32 + quad*8];
        #pragma unroll
        for (int i=0;i<2;i++)
          #pragma unroll
          for (int j=0;j<4;j++)
            P[i][j] = __builtin_amdgcn_mfma_f32_16x16x32_bf16(af[i], bfr[j], P[i][j], 0, 0, 0);
      }
      __syncthreads();
    }

    // decay mask -> Ps
    {
      float cl[4], lrv[4];
      #pragma unroll
      for (int j=0;j<4;j++){
        const int l = l0 + wc + j*16 + l15;
        cl[j] = (float)cd[l];
        if (ISF2) lrv[j] = colv[l];
      }
      #pragma unroll
      for (int i=0;i<2;i++)
        #pragma unroll
        for (int reg=0; reg<4; reg++){
          const int mloc = wr + i*16 + quad*4 + reg;
          const int m = m0 + mloc;
          const float cm2 = (float)cd[m];
          #pragma unroll
          for (int j=0;j<4;j++){
            const int lloc = wc + j*16 + l15;
            const int l = l0 + lloc;
            float v = -P[i][j][reg] * __expf(cm2 - cl[j]);
            if (ISF2) v *= lrv[j];
            if (l > m) v = 0.f;
            Ps[mloc*SP + lloc] = (bf16)v;
          }
        }
    }
    __syncthreads();

    // PV phase: O += Ps . B2-tile (B2 rows n0..n0+127, k from l0), 2 steps of 64
    for (int st=0; st<2; st++){
      {
        const bf16* s = B2 + (long)(n0+rowB)*g.ldb2 + l0 + st*64 + kB;
        #pragma unroll
        for (int p=0;p<4;p++) *(bf16x8*)&Bs[rowB*SB + kB + p*8] = *(const bf16x8*)(s + p*8);
      }
      __syncthreads();
      #pragma unroll
      for (int ch=0; ch<2; ch++){
        bf16x8 af[2], bfr[4];
        #pragma unroll
        for (int i=0;i<2;i++) af[i]  = *(const bf16x8*)&Ps[(wr + i*16 + l15)*SP + st*64 + ch*32 + quad*8];
        #pragma unroll
        for (int j=0;j<4;j++) bfr[j] = *(const bf16x8*)&Bs[(wc + j*16 + l15)*SB + ch*32 + quad*8];
        #pragma unroll
        for (int i=0;i<2;i++)
          #pragma unroll
          for (int j=0;j<4;j++)
            O[i][j] = __builtin_amdgcn_mfma_f32_16x16x32_bf16(af[i], bfr[j], O[i][j], 0, 0, 0);
      }
      __syncthreads();
    }
  }

  // ---- epilogue
  #pragma unroll
  for (int i=0;i<2;i++){
    const int rb = m0 + wr + i*16 + quad*4;
    #pragma unroll
    for (int j=0;j<4;j++){
      const int c = n0 + wc + j*16 + l15;
      #pragma unroll
      for (int reg=0; reg<4; reg++){
        const long co = (long)(rb+reg)*g.ldc + c;
        if (ZSPLIT)     unsafeAtomicAdd(&g.Cf[(long)bz*g.sCf + co], O[i][j][reg]);
        else if (ISF2)  g.Cf[(long)bz*g.sCf + co] = O[i][j][reg];
        else            g.Cb[(long)bz*g.sCb + co] = (bf16)silu_f(O[i][j][reg]);
      }
    }
  }
}

// ===================== helpers =====================
__global__ __launch_bounds__(256)
void conv_multi(const float* __restrict__ a, bf16* __restrict__ oa, long na,
                const float* __restrict__ b, bf16* __restrict__ ob, long nb,
                const float* __restrict__ c, bf16* __restrict__ oc, long nc)
{
  const int job = blockIdx.y;
  const float* src = job==0 ? a : (job==1 ? b : c);
  bf16* dst       = job==0 ? oa : (job==1 ? ob : oc);
  const long n    = job==0 ? na : (job==1 ? nb : nc);
  long i = ((long)blockIdx.x*256 + threadIdx.x)*8;
  if (i >= n) return;
  float4 x = *(const float4*)&src[i];
  float4 y = *(const float4*)&src[i+4];
  bf16x8 o;
  o[0]=(bf16)x.x; o[1]=(bf16)x.y; o[2]=(bf16)x.z; o[3]=(bf16)x.w;
  o[4]=(bf16)y.x; o[5]=(bf16)y.y; o[6]=(bf16)y.z; o[7]=(bf16)y.w;
  *(bf16x8*)&dst[i] = o;
}

__global__ __launch_bounds__(256)
void transpose_qkv(const float* __restrict__ Wq, const float* __restrict__ Wk,
                   const float* __restrict__ Wv, bf16* __restrict__ out)
{
  __shared__ bf16 t[64][72];
  const int z = blockIdx.z;
  const float* ip = z==0 ? Wq : (z==1 ? Wk : Wv);
  bf16* op = out + (long)z*256*256;
  const int r0 = blockIdx.x*64, c0 = blockIdx.y*64;
  const int tid = threadIdx.x;
  const int lr_ = tid>>2, lc = (tid&3)*16;
  #pragma unroll
  for (int q=0;q<4;q++){
    float4 a = *(const float4*)&ip[(long)(r0+lr_)*256 + c0+lc + q*4];
    t[lr_][lc+q*4+0] = (bf16)a.x; t[lr_][lc+q*4+1] = (bf16)a.y;
    t[lr_][lc+q*4+2] = (bf16)a.z; t[lr_][lc+q*4+3] = (bf16)a.w;
  }
  __syncthreads();
  const int oc = tid>>2, orr = (tid&3)*16;
  bf16x8 u, v;
  #pragma unroll
  for (int i=0;i<8;i++){ u[i] = t[orr+i][oc]; v[i] = t[orr+8+i][oc]; }
  *(bf16x8*)&op[(long)(c0+oc)*256 + r0+orr]   = u;
  *(bf16x8*)&op[(long)(c0+oc)*256 + r0+orr+8] = v;
}

__global__ __launch_bounds__(256)
void transpose_f32_bf16(const float* __restrict__ in, bf16* __restrict__ out,
                        int R, int C, long sIn, long sOut)
{
  __shared__ bf16 t[64][72];
  const float* ip = in + (long)blockIdx.z*sIn;
  bf16* op = out + (long)blockIdx.z*sOut;
  const int r0 = blockIdx.x*64, c0 = blockIdx.y*64;
  const int tid = threadIdx.x;
  const int lr_ = tid>>2, lc = (tid&3)*16;
  #pragma unroll
  for (int q=0;q<4;q++){
    float4 a = *(const float4*)&ip[(long)(r0+lr_)*C + c0+lc + q*4];
    t[lr_][lc+q*4+0] = (bf16)a.x; t[lr_][lc+q*4+1] = (bf16)a.y;
    t[lr_][lc+q*4+2] = (bf16)a.z; t[lr_][lc+q*4+3] = (bf16)a.w;
  }
  __syncthreads();
  const int oc = tid>>2, orr = (tid&3)*16;
  bf16x8 u, v;
  #pragma unroll
  for (int i=0;i<8;i++){ u[i] = t[orr+i][oc]; v[i] = t[orr+8+i][oc]; }
  *(bf16x8*)&op[(long)(c0+oc)*R + r0+orr]   = u;
  *(bf16x8*)&op[(long)(c0+oc)*R + r0+orr+8] = v;
}

__global__ __launch_bounds__(256)
void scalar_proj_kernel(const float* __restrict__ x,
                        const float* __restrict__ wlr, const float* __restrict__ blr,
                        const float* __restrict__ wwd, const float* __restrict__ bwd,
                        const float* __restrict__ lbl, const float* __restrict__ lbw,
                        float* __restrict__ lr, float* __restrict__ lw)
{
  const int row  = blockIdx.x*4 + (threadIdx.x >> 6);
  const int lane = threadIdx.x & 63;
  const float4 a = ((const float4*)(x + (long)row*256))[lane];
  const float4 u = ((const float4*)wlr)[lane];
  const float4 w = ((const float4*)wwd)[lane];
  float d1 = a.x*u.x + a.y*u.y + a.z*u.z + a.w*u.w;
  float d2 = a.x*w.x + a.y*w.y + a.z*w.z + a.w*w.w;
  #pragma unroll
  for (int off=32; off; off>>=1) {
    d1 += __shfl_down(d1, off);
    d2 += __shfl_down(d2, off);
  }
  if (lane == 0) {
    float s1 = 1.f/(1.f+expf(-(d1 + blr[0])));
    lr[row] = expf(lbl[0]) * s1;
    float s2 = 1.f/(1.f+expf(-(d2 + bwd[0])));
    lw[row] = logf(1.f - expf(lbw[0]) * s2);
  }
}

// blocks 0..3: per-batch fp64 scan + derived; block 4: bias concat
__global__ __launch_bounds__(256)
void cumsum_kernel(const float* __restrict__ lw, const float* __restrict__ lr,
                   double* __restrict__ cd, float* __restrict__ wdc,
                   float* __restrict__ se1, float* __restrict__ se2, int L,
                   const float* __restrict__ bq, const float* __restrict__ bk,
                   const float* __restrict__ bv, float* __restrict__ bqkv)
{
  const int b = blockIdx.x;
  const int t = threadIdx.x;
  if (b == 4) {
    for (int i = t; i < 768; i += 256)
      bqkv[i] = (i<256) ? bq[i] : ((i<512) ? bk[i-256] : bv[i-512]);
    return;
  }
  const float* lwb = lw + (long)b*L;
  __shared__ double sum_s[256];
  double loc[8];
  double s = 0.0;
  #pragma unroll
  for (int i=0;i<8;i++){ s += (double)lwb[t*8+i]; loc[i] = s; }
  sum_s[t] = s;
  __syncthreads();
  for (int off=1; off<256; off<<=1){
    double v = 0.0;
    if (t >= off) v = sum_s[t-off];
    __syncthreads();
    sum_s[t] += v;
    __syncthreads();
  }
  const double prefix = (t > 0) ? sum_s[t-1] : 0.0;
  const double total  = sum_s[255];
  #pragma unroll
  for (int i=0;i<8;i++){
    double c = prefix + loc[i];
    long idx = (long)b*L + t*8 + i;
    cd[idx]  = c;
    wdc[idx] = (float)exp(c);
    double e = exp(total - c);
    se1[idx] = (float)(-e);
    se2[idx] = (float)(-e) * lr[idx];
  }
}

extern "C" void kernel_launch(void* const* d_in, const int* in_sizes, int n_in,
                              void* d_out, int out_size, void* d_ws, size_t ws_size,
                              hipStream_t stream)
{
  const int Bn = 4, L = 2048, D = 256, H = 512;
  const long LD = (long)L*D, LH = (long)L*H, HD = (long)H*D;

  const float* x   = (const float*)d_in[0];
  const float* W1  = (const float*)d_in[1];
  const float* W2  = (const float*)d_in[2];
  const float* Wq  = (const float*)d_in[3];
  const float* bq  = (const float*)d_in[4];
  const float* Wk  = (const float*)d_in[5];
  const float* bk  = (const float*)d_in[6];
  const float* Wv  = (const float*)d_in[7];
  const float* bv  = (const float*)d_in[8];
  const float* wlr = (const float*)d_in[9];
  const float* blr = (const float*)d_in[10];
  const float* wwd = (const float*)d_in[11];
  const float* bwd = (const float*)d_in[12];
  const float* lbl = (const float*)d_in[13];
  const float* lbw = (const float*)d_in[14];
  (void)in_sizes; (void)n_in; (void)out_size; (void)ws_size;

  float* out0 = (float*)d_out;            // Z2_      [B,L,D]
  float* out1 = out0 + (long)Bn*LD;       // W1_next  [B,H,D]
  float* out2 = out1 + (long)Bn*HD;       // W2_next  [B,D,H]

  char* wsp = (char*)d_ws;
  size_t off = 0;
  auto alloc = [&](size_t bytes)->void*{
    void* p = wsp + off; off += (bytes + 255) & ~(size_t)255; return p;
  };
  bf16* xb    = (bf16*)alloc((size_t)Bn*LD*2);
  bf16* Wqkvt = (bf16*)alloc((size_t)3*D*D*2);
  float* bqkv = (float*)alloc((size_t)3*D*4);
  bf16* W1b  = (bf16*)alloc((size_t)Bn*HD*2);
  bf16* W2b  = (bf16*)alloc((size_t)Bn*HD*2);
  bf16* W2t  = (bf16*)alloc((size_t)Bn*HD*2);
  bf16* Qb   = (bf16*)alloc((size_t)Bn*LD*2);
  bf16* Kb   = (bf16*)alloc((size_t)Bn*LD*2);
  bf16* Kt   = (bf16*)alloc((size_t)Bn*LD*2);
  float* Vf  = (float*)alloc((size_t)Bn*LD*4);
  bf16* Z1b  = (bf16*)alloc((size_t)Bn*LH*2);
  bf16* X2b  = (bf16*)alloc((size_t)Bn*LH*2);
  bf16* X2t  = (bf16*)alloc((size_t)Bn*LH*2);
  bf16* gZb  = (bf16*)alloc((size_t)Bn*LD*2);
  bf16* gZt  = (bf16*)alloc((size_t)Bn*LD*2);
  bf16* A1b  = (bf16*)alloc((size_t)Bn*LH*2);
  bf16* A1t  = (bf16*)alloc((size_t)Bn*LH*2);
  bf16* X2_b = (bf16*)alloc((size_t)Bn*LH*2);
  float* lrb = (float*)alloc((size_t)Bn*L*4);
  float* lwb = (float*)alloc((size_t)Bn*L*4);
  float* wdc = (float*)alloc((size_t)Bn*L*4);
  float* se1 = (float*)alloc((size_t)Bn*L*4);
  float* se2 = (float*)alloc((size_t)Bn*L*4);
  double* cdb = (double*)alloc((size_t)Bn*L*8);

  auto run128 = [&](const MArgs& g, int Z){
    dim3 grid(g.M/128, g.N/64, Z);
    mfma_gemm128<<<grid, 256, 0, stream>>>(g);
  };
  auto run64 = [&](const MArgs& g, int Z){
    dim3 grid(g.M/64, g.N/64, Z);
    mfma_gemm64<<<grid, 256, 0, stream>>>(g);
  };

  // zero out0 (F2 accumulates atomically)
  hipMemsetAsync(out0, 0, (size_t)Bn*LD*4, stream);

  // ---- front matter (merged)
  conv_multi<<<dim3(1024,3), 256, 0, stream>>>(x, xb, Bn*LD, W1, W1b, Bn*HD, W2, W2b, Bn*HD);
  transpose_qkv<<<dim3(4,4,3), 256, 0, stream>>>(Wq, Wk, Wv, Wqkvt);
  transpose_f32_bf16<<<dim3(4,8,Bn), 256, 0, stream>>>(W2, W2t, D, H, HD, HD);
  scalar_proj_kernel<<<dim3(Bn*L/4), 256, 0, stream>>>(x, wlr, blr, wwd, bwd, lbl, lbw, lrb, lwb);
  cumsum_kernel<<<dim3(5), 256, 0, stream>>>(lwb, lrb, cdb, wdc, se1, se2, L, bq, bk, bv, bqkv);

  // ---- fused QKV (M = B*L, N = 768); Kt via Ct
  {
    MArgs g{}; g.A = xb; g.lda = D; g.B = Wqkvt; g.ldb = D;
    g.M = Bn*L; g.N = 3*D; g.K = D; g.mode = 11; g.ldc = 0;
    g.Q = Qb; g.Ko = Kb; g.Vo = Vf; g.bqkv = bqkv;
    g.Ct = Kt; g.sCt = LD; g.ldct = L;
    run128(g, 1);
  }
  // ---- Z1 = K.W1^T ; X2 = silu(Z1); X2t via Ct
  {
    MArgs g{}; g.A = Kb; g.lda = D; g.sA = LD; g.B = W1b; g.ldb = D; g.sB = HD;
    g.M = L; g.N = H; g.K = D; g.mode = 1; g.ldc = H;
    g.Cb = Z1b; g.sCb = LH; g.Cb2 = X2b; g.sCb2 = LH;
    g.Ct = X2t; g.sCt = LH; g.ldct = L; run64(g, Bn);
  }
  // ---- gZ2 = X2.W2^T - V; gZt via Ct
  {
    MArgs g{}; g.A = X2b; g.lda = H; g.sA = LH; g.B = W2b; g.ldb = H; g.sB = HD;
    g.M = L; g.N = D; g.K = H; g.mode = 2; g.ldc = D;
    g.auxf = Vf; g.ldax = D; g.sAuxf = LD; g.Cb = gZb; g.sCb = LD;
    g.Ct = gZt; g.sCt = LD; g.ldct = L; run64(g, Bn);
  }
  // ---- A1 = silu_bwd(Z1)*(gZ2.W2)*lr; A1t via Ct
  {
    MArgs g{}; g.A = gZb; g.lda = D; g.sA = LD; g.B = W2t; g.ldb = D; g.sB = HD;
    g.M = L; g.N = H; g.K = D; g.mode = 3; g.ldc = H;
    g.auxb = Z1b; g.ldax = H; g.sAuxb = LH; g.rowv = lrb; g.sRowv = L;
    g.Cb = A1b; g.sCb = LH;
    g.Ct = A1t; g.sCt = LH; g.ldct = L; run64(g, Bn);
  }
  // ---- F1: X2_ = silu( wdc[m]*(Q.W1^T) + sum_l P1.A1 )
  {
    FArgs f{};
    f.A = Qb;  f.sA = LD;  f.B1 = Kb;  f.sB1 = LD;
    f.B2 = A1t; f.sB2 = LH; f.ldb2 = L;
    f.W = W1b; f.sW = HD;
    f.cd = cdb; f.sCd = L; f.wdc = wdc; f.sWdc = L;
    f.Cb = X2_b; f.sCb = LH; f.ldc = H;
    fused_inner<4,0,0><<<dim3(L/64, H/128, Bn), 256, 0, stream>>>(f);
  }
  // ---- F2: out0 += wdc[m]*(X2_.W2^T) + sum_l P2.gZ2   (z-split band, atomic)
  {
    FArgs f{};
    f.A = X2_b; f.sA = LH; f.B1 = X2b; f.sB1 = LH;
    f.B2 = gZt; f.sB2 = LD; f.ldb2 = L;
    f.W = W2b; f.sW = HD;
    f.cd = cdb; f.sCd = L; f.colv = lrb; f.sColv = L; f.wdc = wdc; f.sWdc = L;
    f.Cf = out0; f.sCf = LD; f.ldc = D;
    fused_inner<8,1,1><<<dim3(L/64, D/128, Bn*2), 256, 0, stream>>>(f);
  }
  // ---- W1_next + W2_next in one launch
  {
    MArgs g1{}; g1.A = A1t; g1.lda = L; g1.sA = LH; g1.B = Kt; g1.ldb = L; g1.sB = LD;
    g1.M = H; g1.N = D; g1.K = L; g1.mode = 10; g1.ldc = D;
    g1.ks = se1; g1.sKs = L; g1.cd = cdb; g1.sCd = L;
    g1.auxf = W1; g1.ldax = D; g1.sAuxf = HD; g1.clp = wdc + (L-1); g1.sClp = L;
    g1.Cf = out1; g1.sCf = HD;

    MArgs g2{}; g2.A = gZt; g2.lda = L; g2.sA = LD; g2.B = X2t; g2.ldb = L; g2.sB = LH;
    g2.M = D; g2.N = H; g2.K = L; g2.mode = 10; g2.ldc = H;
    g2.ks = se2; g2.sKs = L; g2.cd = cdb; g2.sCd = L;
    g2.auxf = W2; g2.ldax = H; g2.sAuxf = HD; g2.clp = wdc + (L-1); g2.sClp = L;
    g2.Cf = out2; g2.sCf = HD;

    wnext_gemm<<<dim3(4,8,8), 256, 0, stream>>>(g1, g2);
  }
}